// Round 9
// baseline (3475.729 us; speedup 1.0000x reference)
//
#include <hip/hip_runtime.h>
#include <math.h>

constexpr int NN = 100000;   // nodes
constexpr int EE = 3200000;  // edges
constexpr int BB = 32;       // graphs
constexpr int LSEQ = 1000;   // text length
constexpr int DD = 128;      // emb dim
constexpr int NH = 3;        // heads gat1
constexpr int HD = 384;      // 3*128
constexpr int NB1 = (NN + 255) / 256;  // scan blocks (391)
constexpr int NMT = (NN + 127) / 128;  // 782 M-tiles

typedef __attribute__((ext_vector_type(8))) short bf16v8;
typedef __attribute__((ext_vector_type(4))) float f32x4;

static __device__ __forceinline__ float lrelu(float x) { return x > 0.f ? x : 0.2f * x; }
static __device__ __forceinline__ float bf2f(unsigned short u) {
  return __uint_as_float(((unsigned)u) << 16);
}
static __device__ __forceinline__ unsigned short f2bf(float f) {
  unsigned x = __float_as_uint(f);
  return (unsigned short)((x + 0x7fffu + ((x >> 16) & 1u)) >> 16);
}

// ---------------- fused prep: converts + weight repacks + zero fills ----------------
constexpr int PB_NF   = (NN * DD / 4) / 256;              // 12500
constexpr int PB_PAD  = (BB * LSEQ * 128 / 4) / 256;      // 4000
constexpr int PB_DEG  = NB1;                              // 391
constexpr int PB_EL2  = (2 * NN + 255) / 256;             // 782 (el2+er2 zero)
constexpr int PB_GP   = (BB * HD + 255) / 256;            // 48
constexpr int PB_TW1  = (128 * 384 + 255) / 256;          // 192
constexpr int PB_TW2  = (384 * 384 + 255) / 256;          // 576
constexpr int PB_TC   = (128 * 384 + 255) / 256;          // 192
constexpr int PREP_BLOCKS = PB_NF + PB_PAD + PB_DEG + PB_EL2 + PB_GP + PB_TW1 + PB_TW2 + 3 * PB_TC;

__global__ void prep_misc(const float* __restrict__ nf, unsigned short* __restrict__ nfbf,
                          const float* __restrict__ pad, unsigned short* __restrict__ padbf,
                          int* __restrict__ deg, float* __restrict__ el2z,
                          unsigned* __restrict__ gpool,
                          const float* __restrict__ W1, unsigned short* __restrict__ Wt1,
                          const float* __restrict__ W2, unsigned short* __restrict__ Wt2,
                          const float* __restrict__ c1w, unsigned short* __restrict__ Wc1,
                          const float* __restrict__ c2w, unsigned short* __restrict__ Wc2,
                          const float* __restrict__ c3w, unsigned short* __restrict__ Wc3) {
  int bx = blockIdx.x, tid = threadIdx.x;
  if (bx < PB_NF) {
    int i = bx * 256 + tid;
    float4 v = ((const float4*)nf)[i];
    ushort4 o;
    o.x = f2bf(v.x); o.y = f2bf(v.y); o.z = f2bf(v.z); o.w = f2bf(v.w);
    ((ushort4*)nfbf)[i] = o;
    return;
  }
  bx -= PB_NF;
  if (bx < PB_PAD) {
    int i = bx * 256 + tid;
    float4 v = ((const float4*)pad)[i];
    ushort4 o;
    o.x = f2bf(v.x); o.y = f2bf(v.y); o.z = f2bf(v.z); o.w = f2bf(v.w);
    ((ushort4*)padbf)[i] = o;
    return;
  }
  bx -= PB_PAD;
  if (bx < PB_DEG) {
    int i = bx * 256 + tid;
    if (i < NN) deg[i] = 0;
    return;
  }
  bx -= PB_DEG;
  if (bx < PB_EL2) {
    int i = bx * 256 + tid;
    if (i < 2 * NN) el2z[i] = 0.f;      // zeroes el2 then er2 (contiguous)
    return;
  }
  bx -= PB_EL2;
  if (bx < PB_GP) {
    int i = bx * 256 + tid;
    if (i < BB * HD) gpool[i] = 0u;
    return;
  }
  bx -= PB_GP;
  if (bx < PB_TW1) {
    int id = bx * 256 + tid;
    if (id < 384 * 128) { int n = id / 128, k = id % 128; Wt1[id] = f2bf(W1[(size_t)k * 384 + n]); }
    return;
  }
  bx -= PB_TW1;
  if (bx < PB_TW2) {
    int id = bx * 256 + tid;
    if (id < 384 * 384) { int n = id / 384, k = id % 384; Wt2[id] = f2bf(W2[(size_t)k * 384 + n]); }
    return;
  }
  bx -= PB_TW2;
  const float* cw = (bx < PB_TC) ? c1w : (bx < 2 * PB_TC) ? c2w : c3w;
  unsigned short* co = (bx < PB_TC) ? Wc1 : (bx < 2 * PB_TC) ? Wc2 : Wc3;
  int id = (bx % PB_TC) * 256 + tid;
  if (id < 128 * 384) {
    int o = id / 384, rem = id % 384;
    int t = rem / 128, i = rem % 128;
    co[id] = f2bf(cw[(size_t)o * 384 + i * 3 + t]);
  }
}

// ---------------- CSR build (rank-saving: atomics only in hist) ----------------
__global__ void hist_k(const int* __restrict__ dst, int* __restrict__ deg,
                       int* __restrict__ rank) {
  int i = blockIdx.x * 256 + threadIdx.x;
  if (i >= EE / 4) return;
  int4 d = ((const int4*)dst)[i];
  int4 r;
  r.x = atomicAdd(&deg[d.x], 1);
  r.y = atomicAdd(&deg[d.y], 1);
  r.z = atomicAdd(&deg[d.z], 1);
  r.w = atomicAdd(&deg[d.w], 1);
  ((int4*)rank)[i] = r;
}

__global__ void scan1_k(const int* __restrict__ deg, int* __restrict__ excl,
                        int* __restrict__ bsum) {
  __shared__ int tmp[256];
  int tid = threadIdx.x;
  int i = blockIdx.x * 256 + tid;
  int v = (i < NN) ? deg[i] : 0;
  tmp[tid] = v;
  __syncthreads();
  for (int off = 1; off < 256; off <<= 1) {
    int t = (tid >= off) ? tmp[tid - off] : 0;
    __syncthreads();
    tmp[tid] += t;
    __syncthreads();
  }
  if (i < NN) excl[i] = tmp[tid] - v;
  if (tid == 255) bsum[blockIdx.x] = tmp[255];
}

__global__ void scan2p(int* __restrict__ bsum) {
  __shared__ int tmp[512];
  int tid = threadIdx.x;
  int v = (tid < NB1) ? bsum[tid] : 0;
  tmp[tid] = v;
  __syncthreads();
  for (int off = 1; off < 512; off <<= 1) {
    int t = (tid >= off) ? tmp[tid - off] : 0;
    __syncthreads();
    tmp[tid] += t;
    __syncthreads();
  }
  if (tid < NB1) bsum[tid] = tmp[tid] - v;
}

__global__ void scan3_k(const int* __restrict__ excl, const int* __restrict__ bsum,
                        int* __restrict__ offs) {
  int i = blockIdx.x * 256 + threadIdx.x;
  if (i < NN) offs[i] = excl[i] + bsum[blockIdx.x];
}

// atomic-free scatter using saved ranks
__global__ void scatter_k(const int* __restrict__ src, const int* __restrict__ dst,
                          const int* __restrict__ rank, const int* __restrict__ offs,
                          int* __restrict__ srcs) {
  int i = blockIdx.x * 256 + threadIdx.x;
  if (i >= EE / 4) return;
  int4 s = ((const int4*)src)[i];
  int4 d = ((const int4*)dst)[i];
  int4 r = ((const int4*)rank)[i];
  srcs[offs[d.x] + r.x] = s.x;
  srcs[offs[d.y] + r.y] = s.y;
  srcs[offs[d.z] + r.z] = s.z;
  srcs[offs[d.w] + r.w] = s.w;
}

// ---------------- persistent-M MFMA GEMM with fused el/er epilogue (bf16 C) ----------------
template <int NKB, bool BRES>
__global__ __launch_bounds__(512) void gemm_nres(const unsigned short* __restrict__ A,
                                                 const unsigned short* __restrict__ Bt,
                                                 unsigned short* __restrict__ C,
                                                 const float* __restrict__ al,
                                                 const float* __restrict__ ar,
                                                 float* __restrict__ el,
                                                 float* __restrict__ er,
                                                 int M, int Nc, int nmt, int mpb) {
  static_assert(!BRES || NKB <= 2, "resident B needs K<=128");
  constexpr int KTOT = NKB * 64;
  __shared__ unsigned short As[2][8192];
  __shared__ unsigned short Bs[16384];
  __shared__ float elbuf[128][4];
  __shared__ float erbuf[128][4];
  int tid = threadIdx.x;
  int lane = tid & 63;
  int wave = tid >> 6;
  int wm = wave >> 2, wn = wave & 3;
  int tile_n = blockIdx.x * 128;
  int rloc = lane >> 3;
  int cs = (lane & 7) ^ rloc;
  const unsigned short* Bb = Bt + (size_t)tile_n * KTOT;

  int c0 = tile_n + wn * 32 + (lane & 15);
  float alv0 = al[c0], alv1 = al[c0 + 16];
  float arv0 = ar[c0], arv1 = ar[c0 + 16];

  int mt0 = blockIdx.y * mpb;
  if (mt0 >= nmt) return;
  int mt1 = min(mt0 + mpb, nmt);

  auto stage_a = [&](int mt, int kb, int buf) {
    const unsigned short* Ab = A + (size_t)mt * 128 * KTOT;
    int mr = M - 1 - mt * 128;
#pragma unroll
    for (int q = 0; q < 2; ++q) {
      int t = wave * 2 + q, r = t * 8 + rloc;
      int ra = r > mr ? mr : r;
      __builtin_amdgcn_global_load_lds(
          (const __attribute__((address_space(1))) void*)(Ab + (size_t)ra * KTOT + kb * 64 + cs * 8),
          (__attribute__((address_space(3))) void*)(&As[buf][t * 512]), 16, 0, 0);
    }
  };
  auto stage_b = [&](int kb, int buf) {
#pragma unroll
    for (int q = 0; q < 2; ++q) {
      int t = wave * 2 + q, r = t * 8 + rloc;
      __builtin_amdgcn_global_load_lds(
          (const __attribute__((address_space(1))) void*)(Bb + (size_t)r * KTOT + kb * 64 + cs * 8),
          (__attribute__((address_space(3))) void*)(&Bs[buf * 8192 + t * 512]), 16, 0, 0);
    }
  };

  f32x4 acc[4][2];
#pragma unroll
  for (int i = 0; i < 4; ++i)
#pragma unroll
    for (int j = 0; j < 2; ++j) acc[i][j] = (f32x4){0.f, 0.f, 0.f, 0.f};

  if constexpr (BRES) {
#pragma unroll
    for (int kb = 0; kb < NKB; ++kb) stage_b(kb, kb);
  } else {
    stage_b(0, 0);
  }
  stage_a(mt0, 0, 0);
  __syncthreads();

  int nsteps = (mt1 - mt0) * NKB;
  for (int i = 0; i < nsteps; ++i) {
    int mt = mt0 + i / NKB;
    int kb = i % NKB;
    int cb = i & 1;
    if (i + 1 < nsteps) {
      int ni = i + 1;
      stage_a(mt0 + ni / NKB, ni % NKB, ni & 1);
      if constexpr (!BRES) stage_b(ni % NKB, ni & 1);
    }
    const unsigned short* Ablk = &As[cb][0];
    const unsigned short* Bblk = BRES ? (Bs + kb * 8192) : (Bs + cb * 8192);
#pragma unroll
    for (int ks = 0; ks < 2; ++ks) {
      int q = ks * 4 + (lane >> 4);
      bf16v8 af[4], bfr[2];
#pragma unroll
      for (int ii = 0; ii < 4; ++ii) {
        int r = wm * 64 + ii * 16 + (lane & 15);
        af[ii] = *(const bf16v8*)&Ablk[r * 64 + ((q ^ (r & 7)) * 8)];
      }
#pragma unroll
      for (int j = 0; j < 2; ++j) {
        int r = wn * 32 + j * 16 + (lane & 15);
        bfr[j] = *(const bf16v8*)&Bblk[r * 64 + ((q ^ (r & 7)) * 8)];
      }
#pragma unroll
      for (int ii = 0; ii < 4; ++ii)
#pragma unroll
        for (int j = 0; j < 2; ++j)
          acc[ii][j] = __builtin_amdgcn_mfma_f32_16x16x32_bf16(af[ii], bfr[j], acc[ii][j], 0, 0, 0);
    }
    if (kb == NKB - 1) {
      // C store (bf16)
#pragma unroll
      for (int ii = 0; ii < 4; ++ii) {
        int row0 = mt * 128 + wm * 64 + ii * 16 + (lane >> 4) * 4;
#pragma unroll
        for (int j = 0; j < 2; ++j) {
          int col = tile_n + wn * 32 + j * 16 + (lane & 15);
#pragma unroll
          for (int p = 0; p < 4; ++p) {
            int row = row0 + p;
            if (row < M) C[(size_t)row * Nc + col] = f2bf(acc[ii][j][p]);
          }
        }
      }
      // el/er partials from fp32 acc
#pragma unroll
      for (int ii = 0; ii < 4; ++ii) {
#pragma unroll
        for (int p = 0; p < 4; ++p) {
          float pe = acc[ii][0][p] * alv0 + acc[ii][1][p] * alv1;
          float pr = acc[ii][0][p] * arv0 + acc[ii][1][p] * arv1;
#pragma unroll
          for (int off = 1; off < 16; off <<= 1) {
            pe += __shfl_xor(pe, off);
            pr += __shfl_xor(pr, off);
          }
          if ((lane & 15) == 0) {
            int rl = wm * 64 + ii * 16 + (lane >> 4) * 4 + p;
            elbuf[rl][wn] = pe;
            erbuf[rl][wn] = pr;
          }
        }
      }
      __syncthreads();
      if (tid < 128) {
        int row = mt * 128 + tid;
        if (row < M) {
          float ev = elbuf[tid][0] + elbuf[tid][1] + elbuf[tid][2] + elbuf[tid][3];
          float rv = erbuf[tid][0] + erbuf[tid][1] + erbuf[tid][2] + erbuf[tid][3];
          if constexpr (BRES) {
            el[row * 4 + blockIdx.x] = ev;
            er[row * 4 + blockIdx.x] = rv;
          } else {
            atomicAdd(&el[row], ev);
            atomicAdd(&er[row], rv);
          }
        }
      }
      // reset acc
#pragma unroll
      for (int ii = 0; ii < 4; ++ii)
#pragma unroll
        for (int j = 0; j < 2; ++j) acc[ii][j] = (f32x4){0.f, 0.f, 0.f, 0.f};
    }
    __syncthreads();
  }
}

// ---------------- conv-GEMM (CNN branch, bf16 out) ----------------
__global__ __launch_bounds__(256) void gemm_mfma(const unsigned short* __restrict__ A,
                                                 int lda,
                                                 const unsigned short* __restrict__ Bt,
                                                 unsigned short* __restrict__ C,
                                                 int M, int K, int Nc,
                                                 const float* __restrict__ bias,
                                                 long aBatch, long cBatch) {
  __shared__ unsigned short As[128 * 64];
  __shared__ unsigned short Bs[128 * 64];
  int lane = threadIdx.x & 63;
  int wave = threadIdx.x >> 6;
  int wm = wave >> 1, wn = wave & 1;
  int tile_m = blockIdx.y * 128;
  int tile_n = blockIdx.x * 128;
  int maxRa = M - 1 - tile_m;
  f32x4 acc[4][4];
#pragma unroll
  for (int i = 0; i < 4; ++i)
#pragma unroll
    for (int j = 0; j < 4; ++j) acc[i][j] = (f32x4){0.f, 0.f, 0.f, 0.f};

  const unsigned short* Ab = A + (size_t)blockIdx.z * aBatch + (size_t)tile_m * lda;
  unsigned short* Cb = C + (size_t)blockIdx.z * cBatch;
  const unsigned short* Bb = Bt + (size_t)tile_n * K;
  int rloc = (lane >> 3);
  int cs = (lane & 7) ^ rloc;

  for (int k0 = 0; k0 < K; k0 += 64) {
#pragma unroll
    for (int q = 0; q < 4; ++q) {
      int t = wave * 4 + q;
      int r = t * 8 + rloc;
      int ra = r > maxRa ? maxRa : r;
      __builtin_amdgcn_global_load_lds(
          (const __attribute__((address_space(1))) void*)(Ab + (size_t)ra * lda + k0 + cs * 8),
          (__attribute__((address_space(3))) void*)(As + t * 512), 16, 0, 0);
      __builtin_amdgcn_global_load_lds(
          (const __attribute__((address_space(1))) void*)(Bb + (size_t)r * K + k0 + cs * 8),
          (__attribute__((address_space(3))) void*)(Bs + t * 512), 16, 0, 0);
    }
    __syncthreads();
#pragma unroll
    for (int ks = 0; ks < 2; ++ks) {
      int q = ks * 4 + (lane >> 4);
      bf16v8 af[4], bfr[4];
#pragma unroll
      for (int i = 0; i < 4; ++i) {
        int r = wm * 64 + i * 16 + (lane & 15);
        af[i] = *(const bf16v8*)&As[r * 64 + ((q ^ (r & 7)) * 8)];
      }
#pragma unroll
      for (int j = 0; j < 4; ++j) {
        int r = wn * 64 + j * 16 + (lane & 15);
        bfr[j] = *(const bf16v8*)&Bs[r * 64 + ((q ^ (r & 7)) * 8)];
      }
#pragma unroll
      for (int i = 0; i < 4; ++i)
#pragma unroll
        for (int j = 0; j < 4; ++j)
          acc[i][j] = __builtin_amdgcn_mfma_f32_16x16x32_bf16(af[i], bfr[j], acc[i][j], 0, 0, 0);
    }
    __syncthreads();
  }
#pragma unroll
  for (int i = 0; i < 4; ++i) {
    int row0 = tile_m + wm * 64 + i * 16 + (lane >> 4) * 4;
#pragma unroll
    for (int j = 0; j < 4; ++j) {
      int col = tile_n + wn * 64 + j * 16 + (lane & 15);
      float bv = bias ? bias[col] : 0.f;
#pragma unroll
      for (int p = 0; p < 4; ++p) {
        int row = row0 + p;
        if (row < M) Cb[(size_t)row * Nc + col] = f2bf(acc[i][j][p] + bv);
      }
    }
  }
}

// ---------------- fused edge softmax + aggregation (bf16 gather, 1x dwordx3/lane) ----------------
// lane owns cols lane*6 .. lane*6+5 (12B of the 768B row).
template <int H>
static __device__ __forceinline__ void agg_body3(const float4 t,
                                                 const unsigned short* __restrict__ hfeat,
                                                 int cbase, float acc[6]) {
  int s2 = __float_as_int(t.w);
  const unsigned short* hrow = hfeat + (size_t)s2 * HD + cbase;
  uint3 v = *(const uint3*)hrow;
  unsigned vv0 = v.x, vv1 = v.y, vv2 = v.z;
#pragma unroll
  for (int k = 0; k < 3; ++k) {
    unsigned vk = (k == 0) ? vv0 : (k == 1) ? vv1 : vv2;
    float wlo, whi;
    if constexpr (H == 3) {
      int clo = cbase + 2 * k;
      wlo = (clo < 128) ? t.x : (clo < 256) ? t.y : t.z;
      whi = (clo + 1 < 128) ? t.x : (clo + 1 < 256) ? t.y : t.z;
    } else {
      wlo = t.x; whi = t.x;
    }
    acc[2 * k] += wlo * bf2f((unsigned short)(vk & 0xffffu));
    acc[2 * k + 1] += whi * bf2f((unsigned short)(vk >> 16));
  }
}

template <int H>
static __device__ __forceinline__ void load_sc(const float* __restrict__ el,
                                               int s, const float erd[H], float sc[H]) {
  if constexpr (H == 3) {
    float4 e = ((const float4*)el)[s];
    sc[0] = lrelu(e.x + erd[0]);
    sc[1] = lrelu(e.y + erd[1]);
    sc[2] = lrelu(e.z + erd[2]);
  } else {
    sc[0] = lrelu(el[s] + erd[0]);
  }
}

// POOL: skip writing outg; instead relu-bias result atomicMax'd into gpool[gid].
template <int H, bool POOL>
__global__ __launch_bounds__(256) void agg_csr3(const int* __restrict__ offs,
                                                const int* __restrict__ deg,
                                                const int* __restrict__ srcs,
                                                const float* __restrict__ el,
                                                const float* __restrict__ er,
                                                const unsigned short* __restrict__ hfeat,
                                                const float* __restrict__ bias,
                                                unsigned short* __restrict__ outg,
                                                const int* __restrict__ gids,
                                                unsigned* __restrict__ gpool) {
  __shared__ float wb[4][64][4];
  int wave = threadIdx.x >> 6, lane = threadIdx.x & 63;
  int d = blockIdx.x * 4 + wave;
  int cbase = lane * 6;
  int o0 = offs[d], dg = deg[d];
  float erd[H];
  if constexpr (H == 3) {
    float4 e = ((const float4*)er)[d];
    erd[0] = e.x; erd[1] = e.y; erd[2] = e.z;
  } else {
    erd[0] = er[d];
  }
  float acc[6] = {0.f, 0.f, 0.f, 0.f, 0.f, 0.f};
  float wsum[H];
#pragma unroll
  for (int h = 0; h < H; ++h) wsum[h] = 0.f;

  if (dg <= 64) {
    bool has = lane < dg;
    int s = has ? srcs[o0 + lane] : 0;
    float sc[H], mh[H];
    load_sc<H>(el, s, erd, sc);
#pragma unroll
    for (int h = 0; h < H; ++h) {
      if (!has) sc[h] = -1e30f;
      mh[h] = sc[h];
#pragma unroll
      for (int off = 1; off < 64; off <<= 1) mh[h] = fmaxf(mh[h], __shfl_xor(mh[h], off));
    }
    float w0 = 0.f, w1 = 0.f, w2 = 0.f;
    if (has) {
      w0 = __expf(sc[0] - mh[0]);
      if constexpr (H == 3) {
        w1 = __expf(sc[1] - mh[1]);
        w2 = __expf(sc[2] - mh[2]);
      }
    }
    wsum[0] = w0;
    if constexpr (H == 3) { wsum[1] = w1; wsum[2] = w2; }
    *(float4*)&wb[wave][lane][0] = make_float4(w0, w1, w2, __int_as_float(s));
#pragma unroll 16
    for (int j = 0; j < dg; ++j) {
      float4 t = *(const float4*)&wb[wave][j][0];
      agg_body3<H>(t, hfeat, cbase, acc);
    }
  } else {
    float mh[H];
#pragma unroll
    for (int h = 0; h < H; ++h) mh[h] = -1e30f;
    for (int e = lane; e < dg; e += 64) {
      int s = srcs[o0 + e];
      float sc[H];
      load_sc<H>(el, s, erd, sc);
#pragma unroll
      for (int h = 0; h < H; ++h) mh[h] = fmaxf(mh[h], sc[h]);
    }
#pragma unroll
    for (int h = 0; h < H; ++h) {
#pragma unroll
      for (int off = 1; off < 64; off <<= 1) mh[h] = fmaxf(mh[h], __shfl_xor(mh[h], off));
    }
    int nch = (dg + 63) >> 6;
    for (int ch = 0; ch < nch; ++ch) {
      int e = ch * 64 + lane;
      bool has = e < dg;
      int s = has ? srcs[o0 + e] : 0;
      float sc[H];
      load_sc<H>(el, s, erd, sc);
      float w0 = 0.f, w1 = 0.f, w2 = 0.f;
      if (has) {
        w0 = __expf(sc[0] - mh[0]);
        if constexpr (H == 3) {
          w1 = __expf(sc[1] - mh[1]);
          w2 = __expf(sc[2] - mh[2]);
        }
      }
      wsum[0] += w0;
      if constexpr (H == 3) { wsum[1] += w1; wsum[2] += w2; }
      *(float4*)&wb[wave][lane][0] = make_float4(w0, w1, w2, __int_as_float(s));
      int cnt = min(64, dg - ch * 64);
#pragma unroll 16
      for (int j = 0; j < cnt; ++j) {
        float4 t = *(const float4*)&wb[wave][j][0];
        agg_body3<H>(t, hfeat, cbase, acc);
      }
    }
  }
#pragma unroll
  for (int h = 0; h < H; ++h) {
#pragma unroll
    for (int off = 1; off < 64; off <<= 1) wsum[h] += __shfl_xor(wsum[h], off);
  }
  float inv0, inv1, inv2;
  if constexpr (H == 3) {
    inv0 = (dg > 0) ? 1.f / wsum[0] : 0.f;
    inv1 = (dg > 0) ? 1.f / wsum[1] : 0.f;
    inv2 = (dg > 0) ? 1.f / wsum[2] : 0.f;
  } else {
    inv0 = inv1 = inv2 = (dg > 0) ? 1.f / wsum[0] : 0.f;
  }
  int gid = POOL ? gids[d] : 0;
  unsigned short* orow = outg + (size_t)d * HD + cbase;
  unsigned pk[3];
#pragma unroll
  for (int k = 0; k < 3; ++k) {
    int clo = cbase + 2 * k, chi = clo + 1;
    float ilo, ihi;
    if constexpr (H == 3) {
      ilo = (clo < 128) ? inv0 : (clo < 256) ? inv1 : inv2;
      ihi = (chi < 128) ? inv0 : (chi < 256) ? inv1 : inv2;
    } else {
      ilo = inv0; ihi = inv0;
    }
    float rlo = fmaxf(acc[2 * k] * ilo + bias[clo], 0.f);
    float rhi = fmaxf(acc[2 * k + 1] * ihi + bias[chi], 0.f);
    pk[k] = (unsigned)f2bf(rlo) | ((unsigned)f2bf(rhi) << 16);
    if constexpr (POOL) {
      atomicMax(&gpool[gid * HD + clo], __float_as_uint(rlo));
      atomicMax(&gpool[gid * HD + chi], __float_as_uint(rhi));
    }
  }
  if constexpr (!POOL) {
    uint3 uv; uv.x = pk[0]; uv.y = pk[1]; uv.z = pk[2];
    *(uint3*)orow = uv;
  }
}

// ---------------- CNN branch: bf16 NHC pools ----------------
__global__ void maxpool_nhc(const unsigned short* __restrict__ in, unsigned short* __restrict__ out,
                            int Lin, int Lout, int total) {
  int idx = blockIdx.x * 256 + threadIdx.x;
  if (idx >= total) return;
  int c = idx & 127;
  int j = (idx >> 7) % Lout;
  int b = idx / (128 * Lout);
  const unsigned short* p = in + ((size_t)b * Lin + j * 3) * 128 + c;
  float m = bf2f(p[0]);
  m = fmaxf(m, bf2f(p[128]));
  m = fmaxf(m, bf2f(p[256]));
  out[idx] = f2bf(m);
}

// ---------------- fused head (includes c3 108-max pooling) ----------------
__global__ __launch_bounds__(256) void head_all(const unsigned* __restrict__ gpool,
                                                const unsigned short* __restrict__ c3bf,
                                                const float* __restrict__ fcgw,
                                                const float* __restrict__ fcgb,
                                                const float* __restrict__ tfw,
                                                const float* __restrict__ tfb,
                                                const float* __restrict__ w1s,
                                                const float* __restrict__ fc1w,
                                                const float* __restrict__ fc1b,
                                                const float* __restrict__ fc2w,
                                                const float* __restrict__ fc2b,
                                                const float* __restrict__ outw,
                                                const float* __restrict__ outb,
                                                float* __restrict__ out) {
  __shared__ float gl[HD];
  __shared__ float fvs[128];
  __shared__ float gcv[128];
  __shared__ float gc1[512];
  __shared__ float gc2[256];
  int b = blockIdx.x, tid = threadIdx.x;
  for (int c = tid; c < HD; c += 256) gl[c] = __uint_as_float(gpool[b * HD + c]);
  if (tid < 128) {
    const unsigned short* p = c3bf + (size_t)b * 108 * 128 + tid;
    float m = bf2f(p[0]);
    for (int t = 1; t < 108; ++t) m = fmaxf(m, bf2f(p[t * 128]));
    fvs[tid] = m;
  }
  __syncthreads();
  float wv = 1.f / (1.f + __expf(-w1s[0]));
  if (tid < 128) {
    float a = fcgb[tid];
    for (int k = 0; k < HD; ++k) a += gl[k] * fcgw[(size_t)k * 128 + tid];
    float g1 = fmaxf(a, 0.f);
    float s = tfb[tid];
    for (int k = 0; k < 128; ++k) s += fvs[k] * tfw[(size_t)k * 128 + tid];
    float s1 = fmaxf(s, 0.f);
    gcv[tid] = (1.f - wv) * g1 + wv * s1;
  }
  __syncthreads();
#pragma unroll
  for (int q = 0; q < 2; ++q) {
    int j = tid + q * 256;
    float a = fc1b[j];
    for (int k = 0; k < 128; ++k) a += gcv[k] * fc1w[(size_t)k * 512 + j];
    gc1[j] = fmaxf(a, 0.f);
  }
  __syncthreads();
  {
    float a = fc2b[tid];
    for (int k = 0; k < 512; ++k) a += gc1[k] * fc2w[(size_t)k * 256 + tid];
    gc2[tid] = fmaxf(a, 0.f);
  }
  __syncthreads();
  if (tid < 64) {
    float p0 = 0.f, p1 = 0.f;
#pragma unroll
    for (int q = 0; q < 4; ++q) {
      float v = gc2[tid + q * 64];
      p0 += v * outw[(tid + q * 64) * 2 + 0];
      p1 += v * outw[(tid + q * 64) * 2 + 1];
    }
#pragma unroll
    for (int off = 32; off; off >>= 1) {
      p0 += __shfl_down(p0, off);
      p1 += __shfl_down(p1, off);
    }
    if (tid == 0) {
      float o0 = fmaxf(p0 + outb[0], 0.f), o1 = fmaxf(p1 + outb[1], 0.f);
      float mm = fmaxf(o0, o1);
      float e0 = __expf(o0 - mm), e1 = __expf(o1 - mm);
      float inv = 1.f / (e0 + e1);
      out[b * 2 + 0] = e0 * inv;
      out[b * 2 + 1] = e1 * inv;
    }
  }
}

extern "C" void kernel_launch(void* const* d_in, const int* in_sizes, int n_in,
                              void* d_out, int out_size, void* d_ws, size_t ws_size,
                              hipStream_t stream) {
  const float* node_feat = (const float*)d_in[0];
  const int*   src  = (const int*)d_in[1];
  const int*   dst  = (const int*)d_in[2];
  const int*   gids = (const int*)d_in[3];
  const float* pad  = (const float*)d_in[4];
  const float* W1   = (const float*)d_in[5];
  const float* al1  = (const float*)d_in[6];
  const float* ar1  = (const float*)d_in[7];
  const float* b1   = (const float*)d_in[8];
  const float* W2   = (const float*)d_in[9];
  const float* al2  = (const float*)d_in[10];
  const float* ar2  = (const float*)d_in[11];
  const float* b2   = (const float*)d_in[12];
  const float* fcgw = (const float*)d_in[13];
  const float* fcgb = (const float*)d_in[14];
  const float* c1w  = (const float*)d_in[15];
  const float* c1b  = (const float*)d_in[16];
  const float* c2w  = (const float*)d_in[17];
  const float* c2b  = (const float*)d_in[18];
  const float* c3w  = (const float*)d_in[19];
  const float* c3b  = (const float*)d_in[20];
  const float* tfw  = (const float*)d_in[21];
  const float* tfb  = (const float*)d_in[22];
  const float* w1s  = (const float*)d_in[23];
  const float* fc1w = (const float*)d_in[24];
  const float* fc1b = (const float*)d_in[25];
  const float* fc2w = (const float*)d_in[26];
  const float* fc2b = (const float*)d_in[27];
  const float* outw = (const float*)d_in[28];
  const float* outb = (const float*)d_in[29];
  float* out = (float*)d_out;
  char* base = (char*)d_ws;

  // -------- workspace layout (bytes) --------
  constexpr size_t SZ_BIG = (size_t)NN * HD * 2;          // 76.8 MB
  unsigned short* hA   = (unsigned short*)(base + 0);     // region A: bf16 h table
  unsigned short* gB   = (unsigned short*)(base + SZ_BIG);// region B: bf16 g
  unsigned short* nfbf = gB;  // bf16 node_feat aliases region B (dead before agg1)
  size_t o = 2 * SZ_BIG;
  unsigned short* Wt1 = (unsigned short*)(base + o); o += 384 * 128 * 2;
  unsigned short* Wt2 = (unsigned short*)(base + o); o += 384 * 384 * 2;
  unsigned short* Wc1 = (unsigned short*)(base + o); o += 128 * 384 * 2;
  unsigned short* Wc2 = (unsigned short*)(base + o); o += 128 * 384 * 2;
  unsigned short* Wc3 = (unsigned short*)(base + o); o += 128 * 384 * 2;
  unsigned short* c3bf = (unsigned short*)(base + o); o += (size_t)BB * 108 * 128 * 2; // persists to head
  int* deg    = (int*)(base + o); o += (size_t)NN * 4;
  int* offs   = (int*)(base + o); o += (size_t)NN * 4;
  int* excl   = (int*)(base + o); o += (size_t)NN * 4;
  int* bsum   = (int*)(base + o); o += 2048;
  int* srcs   = (int*)(base + o); o += (size_t)EE * 4;
  int* rank   = (int*)(base + o); o += (size_t)EE * 4;
  float* el1  = (float*)(base + o); o += (size_t)NN * 4 * 4;   // padded stride 4
  float* er1  = (float*)(base + o); o += (size_t)NN * 4 * 4;
  float* el2  = (float*)(base + o); o += (size_t)NN * 4;       // contiguous with er2
  float* er2  = (float*)(base + o); o += (size_t)NN * 4;
  unsigned* gpool = (unsigned*)(base + o); o += (size_t)BB * HD * 4;

  // CNN scratch inside region A (dead before gemm1 writes hA), all bf16 NHC
  unsigned short* padbf = (unsigned short*)base;
  unsigned short* c1bf  = padbf + (size_t)BB * LSEQ * 128;
  unsigned short* p1bf  = c1bf + (size_t)BB * 998 * 128;
  unsigned short* c2bf  = p1bf + (size_t)BB * 332 * 128;
  unsigned short* p2bf  = c2bf + (size_t)BB * 330 * 128;

  // -------- fused prep --------
  prep_misc<<<PREP_BLOCKS, 256, 0, stream>>>(node_feat, nfbf, pad, padbf, deg, el2, gpool,
                                             W1, Wt1, W2, Wt2, c1w, Wc1, c2w, Wc2, c3w, Wc3);

  // -------- CNN branch --------
  gemm_mfma<<<dim3(1, 8, BB), 256, 0, stream>>>(padbf, 128, Wc1, c1bf, 998, 384, 128, c1b,
                                                (long)LSEQ * 128, (long)998 * 128);
  maxpool_nhc<<<(BB * 332 * 128 + 255) / 256, 256, 0, stream>>>(c1bf, p1bf, 998, 332, BB * 332 * 128);
  gemm_mfma<<<dim3(1, 3, BB), 256, 0, stream>>>(p1bf, 128, Wc2, c2bf, 330, 384, 128, c2b,
                                                (long)332 * 128, (long)330 * 128);
  maxpool_nhc<<<(BB * 110 * 128 + 255) / 256, 256, 0, stream>>>(c2bf, p2bf, 330, 110, BB * 110 * 128);
  gemm_mfma<<<dim3(1, 1, BB), 256, 0, stream>>>(p2bf, 128, Wc3, c3bf, 108, 384, 128, c3b,
                                                (long)110 * 128, (long)108 * 128);

  // -------- CSR build --------
  hist_k<<<EE / 1024, 256, 0, stream>>>(dst, deg, rank);
  scan1_k<<<NB1, 256, 0, stream>>>(deg, excl, bsum);
  scan2p<<<1, 512, 0, stream>>>(bsum);
  scan3_k<<<NB1, 256, 0, stream>>>(excl, bsum, offs);
  scatter_k<<<EE / 1024, 256, 0, stream>>>(src, dst, rank, offs, srcs);

  // -------- GAT layer 1 (GEMM + fused el/er) --------
  gemm_nres<2, true><<<dim3(3, (NMT + 9) / 10), 512, 0, stream>>>(
      nfbf, Wt1, hA, al1, ar1, el1, er1, NN, HD, NMT, 10);
  agg_csr3<3, false><<<NN / 4, 256, 0, stream>>>(offs, deg, srcs, el1, er1, hA, b1, gB,
                                                 nullptr, nullptr);

  // -------- GAT layer 2 (GEMM + fused el/er; agg pools directly) --------
  gemm_nres<6, false><<<dim3(3, (NMT + 9) / 10), 512, 0, stream>>>(
      gB, Wt2, hA, al2, ar2, el2, er2, NN, HD, NMT, 10);
  agg_csr3<1, true><<<NN / 4, 256, 0, stream>>>(offs, deg, srcs, el2, er2, hA, b2, gB,
                                                gids, gpool);

  // -------- fused head --------
  head_all<<<BB, 256, 0, stream>>>(gpool, c3bf, fcgw, fcgb, tfw, tfb, w1s,
                                   fc1w, fc1b, fc2w, fc2b, outw, outb, out);
}

// Round 10
// 1281.474 us; speedup vs baseline: 2.7123x; 2.7123x over previous
//
#include <hip/hip_runtime.h>
#include <math.h>

constexpr int NN = 100000;   // nodes
constexpr int EE = 3200000;  // edges
constexpr int BB = 32;       // graphs
constexpr int LSEQ = 1000;   // text length
constexpr int DD = 128;      // emb dim
constexpr int NH = 3;        // heads gat1
constexpr int HD = 384;      // 3*128
constexpr int NB1 = (NN + 255) / 256;  // scan blocks (391)
constexpr int NMT = (NN + 127) / 128;  // 782 M-tiles

typedef __attribute__((ext_vector_type(8))) short bf16v8;
typedef __attribute__((ext_vector_type(4))) float f32x4;

static __device__ __forceinline__ float lrelu(float x) { return x > 0.f ? x : 0.2f * x; }
static __device__ __forceinline__ float bf2f(unsigned short u) {
  return __uint_as_float(((unsigned)u) << 16);
}
static __device__ __forceinline__ unsigned short f2bf(float f) {
  unsigned x = __float_as_uint(f);
  return (unsigned short)((x + 0x7fffu + ((x >> 16) & 1u)) >> 16);
}

// ---------------- fused prep: converts + weight repacks + zero fills ----------------
constexpr int PB_NF   = (NN * DD / 4) / 256;              // 12500
constexpr int PB_PAD  = (BB * LSEQ * 128 / 4) / 256;      // 4000
constexpr int PB_DEG  = NB1;                              // 391
constexpr int PB_EL2  = (2 * NN + 255) / 256;             // 782 (el2+er2 zero)
constexpr int PB_GP   = (BB * HD + 255) / 256;            // 48
constexpr int PB_TW1  = (128 * 384 + 255) / 256;          // 192
constexpr int PB_TW2  = (384 * 384 + 255) / 256;          // 576
constexpr int PB_TC   = (128 * 384 + 255) / 256;          // 192
constexpr int PREP_BLOCKS = PB_NF + PB_PAD + PB_DEG + PB_EL2 + PB_GP + PB_TW1 + PB_TW2 + 3 * PB_TC;

__global__ void prep_misc(const float* __restrict__ nf, unsigned short* __restrict__ nfbf,
                          const float* __restrict__ pad, unsigned short* __restrict__ padbf,
                          int* __restrict__ deg, float* __restrict__ el2z,
                          unsigned* __restrict__ gpool,
                          const float* __restrict__ W1, unsigned short* __restrict__ Wt1,
                          const float* __restrict__ W2, unsigned short* __restrict__ Wt2,
                          const float* __restrict__ c1w, unsigned short* __restrict__ Wc1,
                          const float* __restrict__ c2w, unsigned short* __restrict__ Wc2,
                          const float* __restrict__ c3w, unsigned short* __restrict__ Wc3) {
  int bx = blockIdx.x, tid = threadIdx.x;
  if (bx < PB_NF) {
    int i = bx * 256 + tid;
    float4 v = ((const float4*)nf)[i];
    ushort4 o;
    o.x = f2bf(v.x); o.y = f2bf(v.y); o.z = f2bf(v.z); o.w = f2bf(v.w);
    ((ushort4*)nfbf)[i] = o;
    return;
  }
  bx -= PB_NF;
  if (bx < PB_PAD) {
    int i = bx * 256 + tid;
    float4 v = ((const float4*)pad)[i];
    ushort4 o;
    o.x = f2bf(v.x); o.y = f2bf(v.y); o.z = f2bf(v.z); o.w = f2bf(v.w);
    ((ushort4*)padbf)[i] = o;
    return;
  }
  bx -= PB_PAD;
  if (bx < PB_DEG) {
    int i = bx * 256 + tid;
    if (i < NN) deg[i] = 0;
    return;
  }
  bx -= PB_DEG;
  if (bx < PB_EL2) {
    int i = bx * 256 + tid;
    if (i < 2 * NN) el2z[i] = 0.f;      // zeroes el2 then er2 (contiguous)
    return;
  }
  bx -= PB_EL2;
  if (bx < PB_GP) {
    int i = bx * 256 + tid;
    if (i < BB * HD) gpool[i] = 0u;
    return;
  }
  bx -= PB_GP;
  if (bx < PB_TW1) {
    int id = bx * 256 + tid;
    if (id < 384 * 128) { int n = id / 128, k = id % 128; Wt1[id] = f2bf(W1[(size_t)k * 384 + n]); }
    return;
  }
  bx -= PB_TW1;
  if (bx < PB_TW2) {
    int id = bx * 256 + tid;
    if (id < 384 * 384) { int n = id / 384, k = id % 384; Wt2[id] = f2bf(W2[(size_t)k * 384 + n]); }
    return;
  }
  bx -= PB_TW2;
  const float* cw = (bx < PB_TC) ? c1w : (bx < 2 * PB_TC) ? c2w : c3w;
  unsigned short* co = (bx < PB_TC) ? Wc1 : (bx < 2 * PB_TC) ? Wc2 : Wc3;
  int id = (bx % PB_TC) * 256 + tid;
  if (id < 128 * 384) {
    int o = id / 384, rem = id % 384;
    int t = rem / 128, i = rem % 128;
    co[id] = f2bf(cw[(size_t)o * 384 + i * 3 + t]);
  }
}

// ---------------- CSR build (rank-saving: atomics only in hist) ----------------
__global__ void hist_k(const int* __restrict__ dst, int* __restrict__ deg,
                       int* __restrict__ rank) {
  int i = blockIdx.x * 256 + threadIdx.x;
  if (i >= EE / 4) return;
  int4 d = ((const int4*)dst)[i];
  int4 r;
  r.x = atomicAdd(&deg[d.x], 1);
  r.y = atomicAdd(&deg[d.y], 1);
  r.z = atomicAdd(&deg[d.z], 1);
  r.w = atomicAdd(&deg[d.w], 1);
  ((int4*)rank)[i] = r;
}

__global__ void scan1_k(const int* __restrict__ deg, int* __restrict__ excl,
                        int* __restrict__ bsum) {
  __shared__ int tmp[256];
  int tid = threadIdx.x;
  int i = blockIdx.x * 256 + tid;
  int v = (i < NN) ? deg[i] : 0;
  tmp[tid] = v;
  __syncthreads();
  for (int off = 1; off < 256; off <<= 1) {
    int t = (tid >= off) ? tmp[tid - off] : 0;
    __syncthreads();
    tmp[tid] += t;
    __syncthreads();
  }
  if (i < NN) excl[i] = tmp[tid] - v;
  if (tid == 255) bsum[blockIdx.x] = tmp[255];
}

__global__ void scan2p(int* __restrict__ bsum) {
  __shared__ int tmp[512];
  int tid = threadIdx.x;
  int v = (tid < NB1) ? bsum[tid] : 0;
  tmp[tid] = v;
  __syncthreads();
  for (int off = 1; off < 512; off <<= 1) {
    int t = (tid >= off) ? tmp[tid - off] : 0;
    __syncthreads();
    tmp[tid] += t;
    __syncthreads();
  }
  if (tid < NB1) bsum[tid] = tmp[tid] - v;
}

__global__ void scan3_k(const int* __restrict__ excl, const int* __restrict__ bsum,
                        int* __restrict__ offs) {
  int i = blockIdx.x * 256 + threadIdx.x;
  if (i < NN) offs[i] = excl[i] + bsum[blockIdx.x];
}

// atomic-free scatter using saved ranks
__global__ void scatter_k(const int* __restrict__ src, const int* __restrict__ dst,
                          const int* __restrict__ rank, const int* __restrict__ offs,
                          int* __restrict__ srcs) {
  int i = blockIdx.x * 256 + threadIdx.x;
  if (i >= EE / 4) return;
  int4 s = ((const int4*)src)[i];
  int4 d = ((const int4*)dst)[i];
  int4 r = ((const int4*)rank)[i];
  srcs[offs[d.x] + r.x] = s.x;
  srcs[offs[d.y] + r.y] = s.y;
  srcs[offs[d.z] + r.z] = s.z;
  srcs[offs[d.w] + r.w] = s.w;
}

// ---------------- persistent-M MFMA GEMM with fused el/er epilogue (bf16 C) ----------------
template <int NKB, bool BRES>
__global__ __launch_bounds__(512) void gemm_nres(const unsigned short* __restrict__ A,
                                                 const unsigned short* __restrict__ Bt,
                                                 unsigned short* __restrict__ C,
                                                 const float* __restrict__ al,
                                                 const float* __restrict__ ar,
                                                 float* __restrict__ el,
                                                 float* __restrict__ er,
                                                 int M, int Nc, int nmt, int mpb) {
  static_assert(!BRES || NKB <= 2, "resident B needs K<=128");
  constexpr int KTOT = NKB * 64;
  __shared__ unsigned short As[2][8192];
  __shared__ unsigned short Bs[16384];
  __shared__ float elbuf[128][4];
  __shared__ float erbuf[128][4];
  int tid = threadIdx.x;
  int lane = tid & 63;
  int wave = tid >> 6;
  int wm = wave >> 2, wn = wave & 3;
  int tile_n = blockIdx.x * 128;
  int rloc = lane >> 3;
  int cs = (lane & 7) ^ rloc;
  const unsigned short* Bb = Bt + (size_t)tile_n * KTOT;

  int c0 = tile_n + wn * 32 + (lane & 15);
  float alv0 = al[c0], alv1 = al[c0 + 16];
  float arv0 = ar[c0], arv1 = ar[c0 + 16];

  int mt0 = blockIdx.y * mpb;
  if (mt0 >= nmt) return;
  int mt1 = min(mt0 + mpb, nmt);

  auto stage_a = [&](int mt, int kb, int buf) {
    const unsigned short* Ab = A + (size_t)mt * 128 * KTOT;
    int mr = M - 1 - mt * 128;
#pragma unroll
    for (int q = 0; q < 2; ++q) {
      int t = wave * 2 + q, r = t * 8 + rloc;
      int ra = r > mr ? mr : r;
      __builtin_amdgcn_global_load_lds(
          (const __attribute__((address_space(1))) void*)(Ab + (size_t)ra * KTOT + kb * 64 + cs * 8),
          (__attribute__((address_space(3))) void*)(&As[buf][t * 512]), 16, 0, 0);
    }
  };
  auto stage_b = [&](int kb, int buf) {
#pragma unroll
    for (int q = 0; q < 2; ++q) {
      int t = wave * 2 + q, r = t * 8 + rloc;
      __builtin_amdgcn_global_load_lds(
          (const __attribute__((address_space(1))) void*)(Bb + (size_t)r * KTOT + kb * 64 + cs * 8),
          (__attribute__((address_space(3))) void*)(&Bs[buf * 8192 + t * 512]), 16, 0, 0);
    }
  };

  f32x4 acc[4][2];
#pragma unroll
  for (int i = 0; i < 4; ++i)
#pragma unroll
    for (int j = 0; j < 2; ++j) acc[i][j] = (f32x4){0.f, 0.f, 0.f, 0.f};

  if constexpr (BRES) {
#pragma unroll
    for (int kb = 0; kb < NKB; ++kb) stage_b(kb, kb);
  } else {
    stage_b(0, 0);
  }
  stage_a(mt0, 0, 0);
  __syncthreads();

  int nsteps = (mt1 - mt0) * NKB;
  for (int i = 0; i < nsteps; ++i) {
    int mt = mt0 + i / NKB;
    int kb = i % NKB;
    int cb = i & 1;
    if (i + 1 < nsteps) {
      int ni = i + 1;
      stage_a(mt0 + ni / NKB, ni % NKB, ni & 1);
      if constexpr (!BRES) stage_b(ni % NKB, ni & 1);
    }
    const unsigned short* Ablk = &As[cb][0];
    const unsigned short* Bblk = BRES ? (Bs + kb * 8192) : (Bs + cb * 8192);
#pragma unroll
    for (int ks = 0; ks < 2; ++ks) {
      int q = ks * 4 + (lane >> 4);
      bf16v8 af[4], bfr[2];
#pragma unroll
      for (int ii = 0; ii < 4; ++ii) {
        int r = wm * 64 + ii * 16 + (lane & 15);
        af[ii] = *(const bf16v8*)&Ablk[r * 64 + ((q ^ (r & 7)) * 8)];
      }
#pragma unroll
      for (int j = 0; j < 2; ++j) {
        int r = wn * 32 + j * 16 + (lane & 15);
        bfr[j] = *(const bf16v8*)&Bblk[r * 64 + ((q ^ (r & 7)) * 8)];
      }
#pragma unroll
      for (int ii = 0; ii < 4; ++ii)
#pragma unroll
        for (int j = 0; j < 2; ++j)
          acc[ii][j] = __builtin_amdgcn_mfma_f32_16x16x32_bf16(af[ii], bfr[j], acc[ii][j], 0, 0, 0);
    }
    if (kb == NKB - 1) {
      // C store (bf16)
#pragma unroll
      for (int ii = 0; ii < 4; ++ii) {
        int row0 = mt * 128 + wm * 64 + ii * 16 + (lane >> 4) * 4;
#pragma unroll
        for (int j = 0; j < 2; ++j) {
          int col = tile_n + wn * 32 + j * 16 + (lane & 15);
#pragma unroll
          for (int p = 0; p < 4; ++p) {
            int row = row0 + p;
            if (row < M) C[(size_t)row * Nc + col] = f2bf(acc[ii][j][p]);
          }
        }
      }
      // el/er partials from fp32 acc
#pragma unroll
      for (int ii = 0; ii < 4; ++ii) {
#pragma unroll
        for (int p = 0; p < 4; ++p) {
          float pe = acc[ii][0][p] * alv0 + acc[ii][1][p] * alv1;
          float pr = acc[ii][0][p] * arv0 + acc[ii][1][p] * arv1;
#pragma unroll
          for (int off = 1; off < 16; off <<= 1) {
            pe += __shfl_xor(pe, off);
            pr += __shfl_xor(pr, off);
          }
          if ((lane & 15) == 0) {
            int rl = wm * 64 + ii * 16 + (lane >> 4) * 4 + p;
            elbuf[rl][wn] = pe;
            erbuf[rl][wn] = pr;
          }
        }
      }
      __syncthreads();
      if (tid < 128) {
        int row = mt * 128 + tid;
        if (row < M) {
          float ev = elbuf[tid][0] + elbuf[tid][1] + elbuf[tid][2] + elbuf[tid][3];
          float rv = erbuf[tid][0] + erbuf[tid][1] + erbuf[tid][2] + erbuf[tid][3];
          if constexpr (BRES) {
            el[row * 4 + blockIdx.x] = ev;
            er[row * 4 + blockIdx.x] = rv;
          } else {
            atomicAdd(&el[row], ev);
            atomicAdd(&er[row], rv);
          }
        }
      }
      // reset acc
#pragma unroll
      for (int ii = 0; ii < 4; ++ii)
#pragma unroll
        for (int j = 0; j < 2; ++j) acc[ii][j] = (f32x4){0.f, 0.f, 0.f, 0.f};
    }
    __syncthreads();
  }
}

// ---------------- conv-GEMM (CNN branch, bf16 out) ----------------
__global__ __launch_bounds__(256) void gemm_mfma(const unsigned short* __restrict__ A,
                                                 int lda,
                                                 const unsigned short* __restrict__ Bt,
                                                 unsigned short* __restrict__ C,
                                                 int M, int K, int Nc,
                                                 const float* __restrict__ bias,
                                                 long aBatch, long cBatch) {
  __shared__ unsigned short As[128 * 64];
  __shared__ unsigned short Bs[128 * 64];
  int lane = threadIdx.x & 63;
  int wave = threadIdx.x >> 6;
  int wm = wave >> 1, wn = wave & 1;
  int tile_m = blockIdx.y * 128;
  int tile_n = blockIdx.x * 128;
  int maxRa = M - 1 - tile_m;
  f32x4 acc[4][4];
#pragma unroll
  for (int i = 0; i < 4; ++i)
#pragma unroll
    for (int j = 0; j < 4; ++j) acc[i][j] = (f32x4){0.f, 0.f, 0.f, 0.f};

  const unsigned short* Ab = A + (size_t)blockIdx.z * aBatch + (size_t)tile_m * lda;
  unsigned short* Cb = C + (size_t)blockIdx.z * cBatch;
  const unsigned short* Bb = Bt + (size_t)tile_n * K;
  int rloc = (lane >> 3);
  int cs = (lane & 7) ^ rloc;

  for (int k0 = 0; k0 < K; k0 += 64) {
#pragma unroll
    for (int q = 0; q < 4; ++q) {
      int t = wave * 4 + q;
      int r = t * 8 + rloc;
      int ra = r > maxRa ? maxRa : r;
      __builtin_amdgcn_global_load_lds(
          (const __attribute__((address_space(1))) void*)(Ab + (size_t)ra * lda + k0 + cs * 8),
          (__attribute__((address_space(3))) void*)(As + t * 512), 16, 0, 0);
      __builtin_amdgcn_global_load_lds(
          (const __attribute__((address_space(1))) void*)(Bb + (size_t)r * K + k0 + cs * 8),
          (__attribute__((address_space(3))) void*)(Bs + t * 512), 16, 0, 0);
    }
    __syncthreads();
#pragma unroll
    for (int ks = 0; ks < 2; ++ks) {
      int q = ks * 4 + (lane >> 4);
      bf16v8 af[4], bfr[4];
#pragma unroll
      for (int i = 0; i < 4; ++i) {
        int r = wm * 64 + i * 16 + (lane & 15);
        af[i] = *(const bf16v8*)&As[r * 64 + ((q ^ (r & 7)) * 8)];
      }
#pragma unroll
      for (int j = 0; j < 4; ++j) {
        int r = wn * 64 + j * 16 + (lane & 15);
        bfr[j] = *(const bf16v8*)&Bs[r * 64 + ((q ^ (r & 7)) * 8)];
      }
#pragma unroll
      for (int i = 0; i < 4; ++i)
#pragma unroll
        for (int j = 0; j < 4; ++j)
          acc[i][j] = __builtin_amdgcn_mfma_f32_16x16x32_bf16(af[i], bfr[j], acc[i][j], 0, 0, 0);
    }
    __syncthreads();
  }
#pragma unroll
  for (int i = 0; i < 4; ++i) {
    int row0 = tile_m + wm * 64 + i * 16 + (lane >> 4) * 4;
#pragma unroll
    for (int j = 0; j < 4; ++j) {
      int col = tile_n + wn * 64 + j * 16 + (lane & 15);
      float bv = bias ? bias[col] : 0.f;
#pragma unroll
      for (int p = 0; p < 4; ++p) {
        int row = row0 + p;
        if (row < M) Cb[(size_t)row * Nc + col] = f2bf(acc[i][j][p] + bv);
      }
    }
  }
}

// ---------------- fused edge softmax + aggregation (bf16 gather, 1x dwordx3/lane) ----------------
// lane owns cols lane*6 .. lane*6+5 (12B of the 768B row).
template <int H>
static __device__ __forceinline__ void agg_body3(const float4 t,
                                                 const unsigned short* __restrict__ hfeat,
                                                 int cbase, float acc[6]) {
  int s2 = __float_as_int(t.w);
  const unsigned short* hrow = hfeat + (size_t)s2 * HD + cbase;
  uint3 v = *(const uint3*)hrow;
  unsigned vv0 = v.x, vv1 = v.y, vv2 = v.z;
#pragma unroll
  for (int k = 0; k < 3; ++k) {
    unsigned vk = (k == 0) ? vv0 : (k == 1) ? vv1 : vv2;
    float wlo, whi;
    if constexpr (H == 3) {
      int clo = cbase + 2 * k;
      wlo = (clo < 128) ? t.x : (clo < 256) ? t.y : t.z;
      whi = (clo + 1 < 128) ? t.x : (clo + 1 < 256) ? t.y : t.z;
    } else {
      wlo = t.x; whi = t.x;
    }
    acc[2 * k] += wlo * bf2f((unsigned short)(vk & 0xffffu));
    acc[2 * k + 1] += whi * bf2f((unsigned short)(vk >> 16));
  }
}

template <int H>
static __device__ __forceinline__ void load_sc(const float* __restrict__ el,
                                               int s, const float erd[H], float sc[H]) {
  if constexpr (H == 3) {
    float4 e = ((const float4*)el)[s];
    sc[0] = lrelu(e.x + erd[0]);
    sc[1] = lrelu(e.y + erd[1]);
    sc[2] = lrelu(e.z + erd[2]);
  } else {
    sc[0] = lrelu(el[s] + erd[0]);
  }
}

template <int H>
__global__ __launch_bounds__(256) void agg_csr3(const int* __restrict__ offs,
                                                const int* __restrict__ deg,
                                                const int* __restrict__ srcs,
                                                const float* __restrict__ el,
                                                const float* __restrict__ er,
                                                const unsigned short* __restrict__ hfeat,
                                                const float* __restrict__ bias,
                                                unsigned short* __restrict__ outg) {
  __shared__ float wb[4][64][4];
  int wave = threadIdx.x >> 6, lane = threadIdx.x & 63;
  int d = blockIdx.x * 4 + wave;
  int cbase = lane * 6;
  int o0 = offs[d], dg = deg[d];
  float erd[H];
  if constexpr (H == 3) {
    float4 e = ((const float4*)er)[d];
    erd[0] = e.x; erd[1] = e.y; erd[2] = e.z;
  } else {
    erd[0] = er[d];
  }
  float acc[6] = {0.f, 0.f, 0.f, 0.f, 0.f, 0.f};
  float wsum[H];
#pragma unroll
  for (int h = 0; h < H; ++h) wsum[h] = 0.f;

  if (dg <= 64) {
    bool has = lane < dg;
    int s = has ? srcs[o0 + lane] : 0;
    float sc[H], mh[H];
    load_sc<H>(el, s, erd, sc);
#pragma unroll
    for (int h = 0; h < H; ++h) {
      if (!has) sc[h] = -1e30f;
      mh[h] = sc[h];
#pragma unroll
      for (int off = 1; off < 64; off <<= 1) mh[h] = fmaxf(mh[h], __shfl_xor(mh[h], off));
    }
    float w0 = 0.f, w1 = 0.f, w2 = 0.f;
    if (has) {
      w0 = __expf(sc[0] - mh[0]);
      if constexpr (H == 3) {
        w1 = __expf(sc[1] - mh[1]);
        w2 = __expf(sc[2] - mh[2]);
      }
    }
    wsum[0] = w0;
    if constexpr (H == 3) { wsum[1] = w1; wsum[2] = w2; }
    *(float4*)&wb[wave][lane][0] = make_float4(w0, w1, w2, __int_as_float(s));
#pragma unroll 16
    for (int j = 0; j < dg; ++j) {
      float4 t = *(const float4*)&wb[wave][j][0];
      agg_body3<H>(t, hfeat, cbase, acc);
    }
  } else {
    float mh[H];
#pragma unroll
    for (int h = 0; h < H; ++h) mh[h] = -1e30f;
    for (int e = lane; e < dg; e += 64) {
      int s = srcs[o0 + e];
      float sc[H];
      load_sc<H>(el, s, erd, sc);
#pragma unroll
      for (int h = 0; h < H; ++h) mh[h] = fmaxf(mh[h], sc[h]);
    }
#pragma unroll
    for (int h = 0; h < H; ++h) {
#pragma unroll
      for (int off = 1; off < 64; off <<= 1) mh[h] = fmaxf(mh[h], __shfl_xor(mh[h], off));
    }
    int nch = (dg + 63) >> 6;
    for (int ch = 0; ch < nch; ++ch) {
      int e = ch * 64 + lane;
      bool has = e < dg;
      int s = has ? srcs[o0 + e] : 0;
      float sc[H];
      load_sc<H>(el, s, erd, sc);
      float w0 = 0.f, w1 = 0.f, w2 = 0.f;
      if (has) {
        w0 = __expf(sc[0] - mh[0]);
        if constexpr (H == 3) {
          w1 = __expf(sc[1] - mh[1]);
          w2 = __expf(sc[2] - mh[2]);
        }
      }
      wsum[0] += w0;
      if constexpr (H == 3) { wsum[1] += w1; wsum[2] += w2; }
      *(float4*)&wb[wave][lane][0] = make_float4(w0, w1, w2, __int_as_float(s));
      int cnt = min(64, dg - ch * 64);
#pragma unroll 16
      for (int j = 0; j < cnt; ++j) {
        float4 t = *(const float4*)&wb[wave][j][0];
        agg_body3<H>(t, hfeat, cbase, acc);
      }
    }
  }
#pragma unroll
  for (int h = 0; h < H; ++h) {
#pragma unroll
    for (int off = 1; off < 64; off <<= 1) wsum[h] += __shfl_xor(wsum[h], off);
  }
  float inv0, inv1, inv2;
  if constexpr (H == 3) {
    inv0 = (dg > 0) ? 1.f / wsum[0] : 0.f;
    inv1 = (dg > 0) ? 1.f / wsum[1] : 0.f;
    inv2 = (dg > 0) ? 1.f / wsum[2] : 0.f;
  } else {
    inv0 = inv1 = inv2 = (dg > 0) ? 1.f / wsum[0] : 0.f;
  }
  unsigned short* orow = outg + (size_t)d * HD + cbase;
  unsigned pk[3];
#pragma unroll
  for (int k = 0; k < 3; ++k) {
    int clo = cbase + 2 * k, chi = clo + 1;
    float ilo, ihi;
    if constexpr (H == 3) {
      ilo = (clo < 128) ? inv0 : (clo < 256) ? inv1 : inv2;
      ihi = (chi < 128) ? inv0 : (chi < 256) ? inv1 : inv2;
    } else {
      ilo = inv0; ihi = inv0;
    }
    float rlo = fmaxf(acc[2 * k] * ilo + bias[clo], 0.f);
    float rhi = fmaxf(acc[2 * k + 1] * ihi + bias[chi], 0.f);
    pk[k] = (unsigned)f2bf(rlo) | ((unsigned)f2bf(rhi) << 16);
  }
  uint3 uv; uv.x = pk[0]; uv.y = pk[1]; uv.z = pk[2];
  *(uint3*)orow = uv;
}

// ---------------- graph max pool (graph_ids sorted; values >= 0) ----------------
__global__ void graph_pool(const unsigned short* __restrict__ g, const int* __restrict__ gid,
                           unsigned* __restrict__ gp) {
  int c = threadIdx.x;
  int n0 = blockIdx.x * 64;
  int nend = min(n0 + 64, NN);
  int cur = gid[n0];
  float mx = 0.f;
  for (int n = n0; n < nend; ++n) {
    int gg = gid[n];
    if (gg != cur) {
      atomicMax(&gp[cur * HD + c], __float_as_uint(mx));
      cur = gg; mx = 0.f;
    }
    mx = fmaxf(mx, bf2f(g[(size_t)n * HD + c]));
  }
  atomicMax(&gp[cur * HD + c], __float_as_uint(mx));
}

// ---------------- CNN branch: bf16 NHC pools ----------------
__global__ void maxpool_nhc(const unsigned short* __restrict__ in, unsigned short* __restrict__ out,
                            int Lin, int Lout, int total) {
  int idx = blockIdx.x * 256 + threadIdx.x;
  if (idx >= total) return;
  int c = idx & 127;
  int j = (idx >> 7) % Lout;
  int b = idx / (128 * Lout);
  const unsigned short* p = in + ((size_t)b * Lin + j * 3) * 128 + c;
  float m = bf2f(p[0]);
  m = fmaxf(m, bf2f(p[128]));
  m = fmaxf(m, bf2f(p[256]));
  out[idx] = f2bf(m);
}

// ---------------- fused head (includes c3 108-max pooling) ----------------
__global__ __launch_bounds__(256) void head_all(const unsigned* __restrict__ gpool,
                                                const unsigned short* __restrict__ c3bf,
                                                const float* __restrict__ fcgw,
                                                const float* __restrict__ fcgb,
                                                const float* __restrict__ tfw,
                                                const float* __restrict__ tfb,
                                                const float* __restrict__ w1s,
                                                const float* __restrict__ fc1w,
                                                const float* __restrict__ fc1b,
                                                const float* __restrict__ fc2w,
                                                const float* __restrict__ fc2b,
                                                const float* __restrict__ outw,
                                                const float* __restrict__ outb,
                                                float* __restrict__ out) {
  __shared__ float gl[HD];
  __shared__ float fvs[128];
  __shared__ float gcv[128];
  __shared__ float gc1[512];
  __shared__ float gc2[256];
  int b = blockIdx.x, tid = threadIdx.x;
  for (int c = tid; c < HD; c += 256) gl[c] = __uint_as_float(gpool[b * HD + c]);
  if (tid < 128) {
    const unsigned short* p = c3bf + (size_t)b * 108 * 128 + tid;
    float m = bf2f(p[0]);
    for (int t = 1; t < 108; ++t) m = fmaxf(m, bf2f(p[t * 128]));
    fvs[tid] = m;
  }
  __syncthreads();
  float wv = 1.f / (1.f + __expf(-w1s[0]));
  if (tid < 128) {
    float a = fcgb[tid];
    for (int k = 0; k < HD; ++k) a += gl[k] * fcgw[(size_t)k * 128 + tid];
    float g1 = fmaxf(a, 0.f);
    float s = tfb[tid];
    for (int k = 0; k < 128; ++k) s += fvs[k] * tfw[(size_t)k * 128 + tid];
    float s1 = fmaxf(s, 0.f);
    gcv[tid] = (1.f - wv) * g1 + wv * s1;
  }
  __syncthreads();
#pragma unroll
  for (int q = 0; q < 2; ++q) {
    int j = tid + q * 256;
    float a = fc1b[j];
    for (int k = 0; k < 128; ++k) a += gcv[k] * fc1w[(size_t)k * 512 + j];
    gc1[j] = fmaxf(a, 0.f);
  }
  __syncthreads();
  {
    float a = fc2b[tid];
    for (int k = 0; k < 512; ++k) a += gc1[k] * fc2w[(size_t)k * 256 + tid];
    gc2[tid] = fmaxf(a, 0.f);
  }
  __syncthreads();
  if (tid < 64) {
    float p0 = 0.f, p1 = 0.f;
#pragma unroll
    for (int q = 0; q < 4; ++q) {
      float v = gc2[tid + q * 64];
      p0 += v * outw[(tid + q * 64) * 2 + 0];
      p1 += v * outw[(tid + q * 64) * 2 + 1];
    }
#pragma unroll
    for (int off = 32; off; off >>= 1) {
      p0 += __shfl_down(p0, off);
      p1 += __shfl_down(p1, off);
    }
    if (tid == 0) {
      float o0 = fmaxf(p0 + outb[0], 0.f), o1 = fmaxf(p1 + outb[1], 0.f);
      float mm = fmaxf(o0, o1);
      float e0 = __expf(o0 - mm), e1 = __expf(o1 - mm);
      float inv = 1.f / (e0 + e1);
      out[b * 2 + 0] = e0 * inv;
      out[b * 2 + 1] = e1 * inv;
    }
  }
}

extern "C" void kernel_launch(void* const* d_in, const int* in_sizes, int n_in,
                              void* d_out, int out_size, void* d_ws, size_t ws_size,
                              hipStream_t stream) {
  const float* node_feat = (const float*)d_in[0];
  const int*   src  = (const int*)d_in[1];
  const int*   dst  = (const int*)d_in[2];
  const int*   gids = (const int*)d_in[3];
  const float* pad  = (const float*)d_in[4];
  const float* W1   = (const float*)d_in[5];
  const float* al1  = (const float*)d_in[6];
  const float* ar1  = (const float*)d_in[7];
  const float* b1   = (const float*)d_in[8];
  const float* W2   = (const float*)d_in[9];
  const float* al2  = (const float*)d_in[10];
  const float* ar2  = (const float*)d_in[11];
  const float* b2   = (const float*)d_in[12];
  const float* fcgw = (const float*)d_in[13];
  const float* fcgb = (const float*)d_in[14];
  const float* c1w  = (const float*)d_in[15];
  const float* c1b  = (const float*)d_in[16];
  const float* c2w  = (const float*)d_in[17];
  const float* c2b  = (const float*)d_in[18];
  const float* c3w  = (const float*)d_in[19];
  const float* c3b  = (const float*)d_in[20];
  const float* tfw  = (const float*)d_in[21];
  const float* tfb  = (const float*)d_in[22];
  const float* w1s  = (const float*)d_in[23];
  const float* fc1w = (const float*)d_in[24];
  const float* fc1b = (const float*)d_in[25];
  const float* fc2w = (const float*)d_in[26];
  const float* fc2b = (const float*)d_in[27];
  const float* outw = (const float*)d_in[28];
  const float* outb = (const float*)d_in[29];
  float* out = (float*)d_out;
  char* base = (char*)d_ws;

  // -------- workspace layout (bytes) --------
  constexpr size_t SZ_BIG = (size_t)NN * HD * 2;          // 76.8 MB
  unsigned short* hA   = (unsigned short*)(base + 0);     // region A: bf16 h table
  unsigned short* gB   = (unsigned short*)(base + SZ_BIG);// region B: bf16 g
  unsigned short* nfbf = gB;  // bf16 node_feat aliases region B (dead before agg1)
  size_t o = 2 * SZ_BIG;
  unsigned short* Wt1 = (unsigned short*)(base + o); o += 384 * 128 * 2;
  unsigned short* Wt2 = (unsigned short*)(base + o); o += 384 * 384 * 2;
  unsigned short* Wc1 = (unsigned short*)(base + o); o += 128 * 384 * 2;
  unsigned short* Wc2 = (unsigned short*)(base + o); o += 128 * 384 * 2;
  unsigned short* Wc3 = (unsigned short*)(base + o); o += 128 * 384 * 2;
  unsigned short* c3bf = (unsigned short*)(base + o); o += (size_t)BB * 108 * 128 * 2; // persists to head
  int* deg    = (int*)(base + o); o += (size_t)NN * 4;
  int* offs   = (int*)(base + o); o += (size_t)NN * 4;
  int* excl   = (int*)(base + o); o += (size_t)NN * 4;
  int* bsum   = (int*)(base + o); o += 2048;
  int* srcs   = (int*)(base + o); o += (size_t)EE * 4;
  int* rank   = (int*)(base + o); o += (size_t)EE * 4;
  float* el1  = (float*)(base + o); o += (size_t)NN * 4 * 4;   // padded stride 4
  float* er1  = (float*)(base + o); o += (size_t)NN * 4 * 4;
  float* el2  = (float*)(base + o); o += (size_t)NN * 4;       // contiguous with er2
  float* er2  = (float*)(base + o); o += (size_t)NN * 4;
  unsigned* gpool = (unsigned*)(base + o); o += (size_t)BB * HD * 4;

  // CNN scratch inside region A (dead before gemm1 writes hA), all bf16 NHC
  unsigned short* padbf = (unsigned short*)base;
  unsigned short* c1bf  = padbf + (size_t)BB * LSEQ * 128;
  unsigned short* p1bf  = c1bf + (size_t)BB * 998 * 128;
  unsigned short* c2bf  = p1bf + (size_t)BB * 332 * 128;
  unsigned short* p2bf  = c2bf + (size_t)BB * 330 * 128;

  // -------- fused prep --------
  prep_misc<<<PREP_BLOCKS, 256, 0, stream>>>(node_feat, nfbf, pad, padbf, deg, el2, gpool,
                                             W1, Wt1, W2, Wt2, c1w, Wc1, c2w, Wc2, c3w, Wc3);

  // -------- CNN branch --------
  gemm_mfma<<<dim3(1, 8, BB), 256, 0, stream>>>(padbf, 128, Wc1, c1bf, 998, 384, 128, c1b,
                                                (long)LSEQ * 128, (long)998 * 128);
  maxpool_nhc<<<(BB * 332 * 128 + 255) / 256, 256, 0, stream>>>(c1bf, p1bf, 998, 332, BB * 332 * 128);
  gemm_mfma<<<dim3(1, 3, BB), 256, 0, stream>>>(p1bf, 128, Wc2, c2bf, 330, 384, 128, c2b,
                                                (long)332 * 128, (long)330 * 128);
  maxpool_nhc<<<(BB * 110 * 128 + 255) / 256, 256, 0, stream>>>(c2bf, p2bf, 330, 110, BB * 110 * 128);
  gemm_mfma<<<dim3(1, 1, BB), 256, 0, stream>>>(p2bf, 128, Wc3, c3bf, 108, 384, 128, c3b,
                                                (long)110 * 128, (long)108 * 128);

  // -------- CSR build --------
  hist_k<<<EE / 1024, 256, 0, stream>>>(dst, deg, rank);
  scan1_k<<<NB1, 256, 0, stream>>>(deg, excl, bsum);
  scan2p<<<1, 512, 0, stream>>>(bsum);
  scan3_k<<<NB1, 256, 0, stream>>>(excl, bsum, offs);
  scatter_k<<<EE / 1024, 256, 0, stream>>>(src, dst, rank, offs, srcs);

  // -------- GAT layer 1 (GEMM + fused el/er) --------
  gemm_nres<2, true><<<dim3(3, (NMT + 9) / 10), 512, 0, stream>>>(
      nfbf, Wt1, hA, al1, ar1, el1, er1, NN, HD, NMT, 10);
  agg_csr3<3><<<NN / 4, 256, 0, stream>>>(offs, deg, srcs, el1, er1, hA, b1, gB);

  // -------- GAT layer 2 (GEMM + fused el/er) --------
  gemm_nres<6, false><<<dim3(3, (NMT + 9) / 10), 512, 0, stream>>>(
      gB, Wt2, hA, al2, ar2, el2, er2, NN, HD, NMT, 10);
  agg_csr3<1><<<NN / 4, 256, 0, stream>>>(offs, deg, srcs, el2, er2, hA, b2, gB);

  // -------- graph pooling + fused head --------
  graph_pool<<<(NN + 63) / 64, 384, 0, stream>>>(gB, gids, gpool);
  head_all<<<BB, 256, 0, stream>>>(gpool, c3bf, fcgw, fcgb, tfw, tfb, w1s,
                                   fc1w, fc1b, fc2w, fc2b, outw, outb, out);
}

// Round 11
// 1262.138 us; speedup vs baseline: 2.7538x; 1.0153x over previous
//
#include <hip/hip_runtime.h>
#include <math.h>

constexpr int NN = 100000;   // nodes
constexpr int EE = 3200000;  // edges
constexpr int BB = 32;       // graphs
constexpr int LSEQ = 1000;   // text length
constexpr int DD = 128;      // emb dim
constexpr int NH = 3;        // heads gat1
constexpr int HD = 384;      // 3*128
constexpr int NB1 = (NN + 255) / 256;  // scan blocks (391)
constexpr int NMT = (NN + 127) / 128;  // 782 M-tiles

typedef __attribute__((ext_vector_type(8))) short bf16v8;
typedef __attribute__((ext_vector_type(4))) float f32x4;

static __device__ __forceinline__ float lrelu(float x) { return x > 0.f ? x : 0.2f * x; }
static __device__ __forceinline__ float bf2f(unsigned short u) {
  return __uint_as_float(((unsigned)u) << 16);
}
static __device__ __forceinline__ unsigned short f2bf(float f) {
  unsigned x = __float_as_uint(f);
  return (unsigned short)((x + 0x7fffu + ((x >> 16) & 1u)) >> 16);
}

// ---------------- fused prep: converts + weight repacks + zero fills ----------------
constexpr int PB_NF   = (NN * DD / 4) / 256;              // 12500
constexpr int PB_PAD  = (BB * LSEQ * 128 / 4) / 256;      // 4000
constexpr int PB_DEG  = NB1;                              // 391
constexpr int PB_EL2  = (2 * NN + 255) / 256;             // 782 (el2+er2 zero)
constexpr int PB_GP   = (BB * HD + 255) / 256;            // 48
constexpr int PB_TW1  = (128 * 384 + 255) / 256;          // 192
constexpr int PB_TW2  = (384 * 384 + 255) / 256;          // 576
constexpr int PB_TC   = (128 * 384 + 255) / 256;          // 192
constexpr int PREP_BLOCKS = PB_NF + PB_PAD + PB_DEG + PB_EL2 + PB_GP + PB_TW1 + PB_TW2 + 3 * PB_TC;

__global__ void prep_misc(const float* __restrict__ nf, unsigned short* __restrict__ nfbf,
                          const float* __restrict__ pad, unsigned short* __restrict__ padbf,
                          int* __restrict__ deg, float* __restrict__ el2z,
                          unsigned* __restrict__ gpool,
                          const float* __restrict__ W1, unsigned short* __restrict__ Wt1,
                          const float* __restrict__ W2, unsigned short* __restrict__ Wt2,
                          const float* __restrict__ c1w, unsigned short* __restrict__ Wc1,
                          const float* __restrict__ c2w, unsigned short* __restrict__ Wc2,
                          const float* __restrict__ c3w, unsigned short* __restrict__ Wc3) {
  int bx = blockIdx.x, tid = threadIdx.x;
  if (bx < PB_NF) {
    int i = bx * 256 + tid;
    float4 v = ((const float4*)nf)[i];
    ushort4 o;
    o.x = f2bf(v.x); o.y = f2bf(v.y); o.z = f2bf(v.z); o.w = f2bf(v.w);
    ((ushort4*)nfbf)[i] = o;
    return;
  }
  bx -= PB_NF;
  if (bx < PB_PAD) {
    int i = bx * 256 + tid;
    float4 v = ((const float4*)pad)[i];
    ushort4 o;
    o.x = f2bf(v.x); o.y = f2bf(v.y); o.z = f2bf(v.z); o.w = f2bf(v.w);
    ((ushort4*)padbf)[i] = o;
    return;
  }
  bx -= PB_PAD;
  if (bx < PB_DEG) {
    int i = bx * 256 + tid;
    if (i < NN) deg[i] = 0;
    return;
  }
  bx -= PB_DEG;
  if (bx < PB_EL2) {
    int i = bx * 256 + tid;
    if (i < 2 * NN) el2z[i] = 0.f;      // zeroes el2 then er2 (contiguous)
    return;
  }
  bx -= PB_EL2;
  if (bx < PB_GP) {
    int i = bx * 256 + tid;
    if (i < BB * HD) gpool[i] = 0u;
    return;
  }
  bx -= PB_GP;
  if (bx < PB_TW1) {
    int id = bx * 256 + tid;
    if (id < 384 * 128) { int n = id / 128, k = id % 128; Wt1[id] = f2bf(W1[(size_t)k * 384 + n]); }
    return;
  }
  bx -= PB_TW1;
  if (bx < PB_TW2) {
    int id = bx * 256 + tid;
    if (id < 384 * 384) { int n = id / 384, k = id % 384; Wt2[id] = f2bf(W2[(size_t)k * 384 + n]); }
    return;
  }
  bx -= PB_TW2;
  const float* cw = (bx < PB_TC) ? c1w : (bx < 2 * PB_TC) ? c2w : c3w;
  unsigned short* co = (bx < PB_TC) ? Wc1 : (bx < 2 * PB_TC) ? Wc2 : Wc3;
  int id = (bx % PB_TC) * 256 + tid;
  if (id < 128 * 384) {
    int o = id / 384, rem = id % 384;
    int t = rem / 128, i = rem % 128;
    co[id] = f2bf(cw[(size_t)o * 384 + i * 3 + t]);
  }
}

// ---------------- CSR build (rank-saving: atomics only in hist) ----------------
__global__ void hist_k(const int* __restrict__ dst, int* __restrict__ deg,
                       int* __restrict__ rank) {
  int i = blockIdx.x * 256 + threadIdx.x;
  if (i >= EE / 4) return;
  int4 d = ((const int4*)dst)[i];
  int4 r;
  r.x = atomicAdd(&deg[d.x], 1);
  r.y = atomicAdd(&deg[d.y], 1);
  r.z = atomicAdd(&deg[d.z], 1);
  r.w = atomicAdd(&deg[d.w], 1);
  ((int4*)rank)[i] = r;
}

__global__ void scan1_k(const int* __restrict__ deg, int* __restrict__ excl,
                        int* __restrict__ bsum) {
  __shared__ int tmp[256];
  int tid = threadIdx.x;
  int i = blockIdx.x * 256 + tid;
  int v = (i < NN) ? deg[i] : 0;
  tmp[tid] = v;
  __syncthreads();
  for (int off = 1; off < 256; off <<= 1) {
    int t = (tid >= off) ? tmp[tid - off] : 0;
    __syncthreads();
    tmp[tid] += t;
    __syncthreads();
  }
  if (i < NN) excl[i] = tmp[tid] - v;
  if (tid == 255) bsum[blockIdx.x] = tmp[255];
}

__global__ void scan2p(int* __restrict__ bsum) {
  __shared__ int tmp[512];
  int tid = threadIdx.x;
  int v = (tid < NB1) ? bsum[tid] : 0;
  tmp[tid] = v;
  __syncthreads();
  for (int off = 1; off < 512; off <<= 1) {
    int t = (tid >= off) ? tmp[tid - off] : 0;
    __syncthreads();
    tmp[tid] += t;
    __syncthreads();
  }
  if (tid < NB1) bsum[tid] = tmp[tid] - v;
}

__global__ void scan3_k(const int* __restrict__ excl, const int* __restrict__ bsum,
                        int* __restrict__ offs) {
  int i = blockIdx.x * 256 + threadIdx.x;
  if (i < NN) offs[i] = excl[i] + bsum[blockIdx.x];
}

// atomic-free scatter using saved ranks
__global__ void scatter_k(const int* __restrict__ src, const int* __restrict__ dst,
                          const int* __restrict__ rank, const int* __restrict__ offs,
                          int* __restrict__ srcs) {
  int i = blockIdx.x * 256 + threadIdx.x;
  if (i >= EE / 4) return;
  int4 s = ((const int4*)src)[i];
  int4 d = ((const int4*)dst)[i];
  int4 r = ((const int4*)rank)[i];
  srcs[offs[d.x] + r.x] = s.x;
  srcs[offs[d.y] + r.y] = s.y;
  srcs[offs[d.z] + r.z] = s.z;
  srcs[offs[d.w] + r.w] = s.w;
}

// ---------------- persistent-M MFMA GEMM with fused el/er epilogue (bf16 C) ----------------
template <int NKB, bool BRES>
__global__ __launch_bounds__(512) void gemm_nres(const unsigned short* __restrict__ A,
                                                 const unsigned short* __restrict__ Bt,
                                                 unsigned short* __restrict__ C,
                                                 const float* __restrict__ al,
                                                 const float* __restrict__ ar,
                                                 float* __restrict__ el,
                                                 float* __restrict__ er,
                                                 int M, int Nc, int nmt, int mpb) {
  static_assert(!BRES || NKB <= 2, "resident B needs K<=128");
  constexpr int KTOT = NKB * 64;
  __shared__ unsigned short As[2][8192];
  __shared__ unsigned short Bs[16384];
  __shared__ float elbuf[128][4];
  __shared__ float erbuf[128][4];
  int tid = threadIdx.x;
  int lane = tid & 63;
  int wave = tid >> 6;
  int wm = wave >> 2, wn = wave & 3;
  int tile_n = blockIdx.x * 128;
  int rloc = lane >> 3;
  int cs = (lane & 7) ^ rloc;
  const unsigned short* Bb = Bt + (size_t)tile_n * KTOT;

  int c0 = tile_n + wn * 32 + (lane & 15);
  float alv0 = al[c0], alv1 = al[c0 + 16];
  float arv0 = ar[c0], arv1 = ar[c0 + 16];

  int mt0 = blockIdx.y * mpb;
  if (mt0 >= nmt) return;
  int mt1 = min(mt0 + mpb, nmt);

  auto stage_a = [&](int mt, int kb, int buf) {
    const unsigned short* Ab = A + (size_t)mt * 128 * KTOT;
    int mr = M - 1 - mt * 128;
#pragma unroll
    for (int q = 0; q < 2; ++q) {
      int t = wave * 2 + q, r = t * 8 + rloc;
      int ra = r > mr ? mr : r;
      __builtin_amdgcn_global_load_lds(
          (const __attribute__((address_space(1))) void*)(Ab + (size_t)ra * KTOT + kb * 64 + cs * 8),
          (__attribute__((address_space(3))) void*)(&As[buf][t * 512]), 16, 0, 0);
    }
  };
  auto stage_b = [&](int kb, int buf) {
#pragma unroll
    for (int q = 0; q < 2; ++q) {
      int t = wave * 2 + q, r = t * 8 + rloc;
      __builtin_amdgcn_global_load_lds(
          (const __attribute__((address_space(1))) void*)(Bb + (size_t)r * KTOT + kb * 64 + cs * 8),
          (__attribute__((address_space(3))) void*)(&Bs[buf * 8192 + t * 512]), 16, 0, 0);
    }
  };

  f32x4 acc[4][2];
#pragma unroll
  for (int i = 0; i < 4; ++i)
#pragma unroll
    for (int j = 0; j < 2; ++j) acc[i][j] = (f32x4){0.f, 0.f, 0.f, 0.f};

  if constexpr (BRES) {
#pragma unroll
    for (int kb = 0; kb < NKB; ++kb) stage_b(kb, kb);
  } else {
    stage_b(0, 0);
  }
  stage_a(mt0, 0, 0);
  __syncthreads();

  int nsteps = (mt1 - mt0) * NKB;
  for (int i = 0; i < nsteps; ++i) {
    int mt = mt0 + i / NKB;
    int kb = i % NKB;
    int cb = i & 1;
    if (i + 1 < nsteps) {
      int ni = i + 1;
      stage_a(mt0 + ni / NKB, ni % NKB, ni & 1);
      if constexpr (!BRES) stage_b(ni % NKB, ni & 1);
    }
    const unsigned short* Ablk = &As[cb][0];
    const unsigned short* Bblk = BRES ? (Bs + kb * 8192) : (Bs + cb * 8192);
#pragma unroll
    for (int ks = 0; ks < 2; ++ks) {
      int q = ks * 4 + (lane >> 4);
      bf16v8 af[4], bfr[2];
#pragma unroll
      for (int ii = 0; ii < 4; ++ii) {
        int r = wm * 64 + ii * 16 + (lane & 15);
        af[ii] = *(const bf16v8*)&Ablk[r * 64 + ((q ^ (r & 7)) * 8)];
      }
#pragma unroll
      for (int j = 0; j < 2; ++j) {
        int r = wn * 32 + j * 16 + (lane & 15);
        bfr[j] = *(const bf16v8*)&Bblk[r * 64 + ((q ^ (r & 7)) * 8)];
      }
#pragma unroll
      for (int ii = 0; ii < 4; ++ii)
#pragma unroll
        for (int j = 0; j < 2; ++j)
          acc[ii][j] = __builtin_amdgcn_mfma_f32_16x16x32_bf16(af[ii], bfr[j], acc[ii][j], 0, 0, 0);
    }
    if (kb == NKB - 1) {
      // C store (bf16)
#pragma unroll
      for (int ii = 0; ii < 4; ++ii) {
        int row0 = mt * 128 + wm * 64 + ii * 16 + (lane >> 4) * 4;
#pragma unroll
        for (int j = 0; j < 2; ++j) {
          int col = tile_n + wn * 32 + j * 16 + (lane & 15);
#pragma unroll
          for (int p = 0; p < 4; ++p) {
            int row = row0 + p;
            if (row < M) C[(size_t)row * Nc + col] = f2bf(acc[ii][j][p]);
          }
        }
      }
      // el/er partials from fp32 acc
#pragma unroll
      for (int ii = 0; ii < 4; ++ii) {
#pragma unroll
        for (int p = 0; p < 4; ++p) {
          float pe = acc[ii][0][p] * alv0 + acc[ii][1][p] * alv1;
          float pr = acc[ii][0][p] * arv0 + acc[ii][1][p] * arv1;
#pragma unroll
          for (int off = 1; off < 16; off <<= 1) {
            pe += __shfl_xor(pe, off);
            pr += __shfl_xor(pr, off);
          }
          if ((lane & 15) == 0) {
            int rl = wm * 64 + ii * 16 + (lane >> 4) * 4 + p;
            elbuf[rl][wn] = pe;
            erbuf[rl][wn] = pr;
          }
        }
      }
      __syncthreads();
      if (tid < 128) {
        int row = mt * 128 + tid;
        if (row < M) {
          float ev = elbuf[tid][0] + elbuf[tid][1] + elbuf[tid][2] + elbuf[tid][3];
          float rv = erbuf[tid][0] + erbuf[tid][1] + erbuf[tid][2] + erbuf[tid][3];
          if constexpr (BRES) {
            el[row * 4 + blockIdx.x] = ev;
            er[row * 4 + blockIdx.x] = rv;
          } else {
            atomicAdd(&el[row], ev);
            atomicAdd(&er[row], rv);
          }
        }
      }
      // reset acc
#pragma unroll
      for (int ii = 0; ii < 4; ++ii)
#pragma unroll
        for (int j = 0; j < 2; ++j) acc[ii][j] = (f32x4){0.f, 0.f, 0.f, 0.f};
    }
    __syncthreads();
  }
}

// ---------------- conv-GEMM (CNN branch, bf16 out) ----------------
__global__ __launch_bounds__(256) void gemm_mfma(const unsigned short* __restrict__ A,
                                                 int lda,
                                                 const unsigned short* __restrict__ Bt,
                                                 unsigned short* __restrict__ C,
                                                 int M, int K, int Nc,
                                                 const float* __restrict__ bias,
                                                 long aBatch, long cBatch) {
  __shared__ unsigned short As[128 * 64];
  __shared__ unsigned short Bs[128 * 64];
  int lane = threadIdx.x & 63;
  int wave = threadIdx.x >> 6;
  int wm = wave >> 1, wn = wave & 1;
  int tile_m = blockIdx.y * 128;
  int tile_n = blockIdx.x * 128;
  int maxRa = M - 1 - tile_m;
  f32x4 acc[4][4];
#pragma unroll
  for (int i = 0; i < 4; ++i)
#pragma unroll
    for (int j = 0; j < 4; ++j) acc[i][j] = (f32x4){0.f, 0.f, 0.f, 0.f};

  const unsigned short* Ab = A + (size_t)blockIdx.z * aBatch + (size_t)tile_m * lda;
  unsigned short* Cb = C + (size_t)blockIdx.z * cBatch;
  const unsigned short* Bb = Bt + (size_t)tile_n * K;
  int rloc = (lane >> 3);
  int cs = (lane & 7) ^ rloc;

  for (int k0 = 0; k0 < K; k0 += 64) {
#pragma unroll
    for (int q = 0; q < 4; ++q) {
      int t = wave * 4 + q;
      int r = t * 8 + rloc;
      int ra = r > maxRa ? maxRa : r;
      __builtin_amdgcn_global_load_lds(
          (const __attribute__((address_space(1))) void*)(Ab + (size_t)ra * lda + k0 + cs * 8),
          (__attribute__((address_space(3))) void*)(As + t * 512), 16, 0, 0);
      __builtin_amdgcn_global_load_lds(
          (const __attribute__((address_space(1))) void*)(Bb + (size_t)r * K + k0 + cs * 8),
          (__attribute__((address_space(3))) void*)(Bs + t * 512), 16, 0, 0);
    }
    __syncthreads();
#pragma unroll
    for (int ks = 0; ks < 2; ++ks) {
      int q = ks * 4 + (lane >> 4);
      bf16v8 af[4], bfr[4];
#pragma unroll
      for (int i = 0; i < 4; ++i) {
        int r = wm * 64 + i * 16 + (lane & 15);
        af[i] = *(const bf16v8*)&As[r * 64 + ((q ^ (r & 7)) * 8)];
      }
#pragma unroll
      for (int j = 0; j < 4; ++j) {
        int r = wn * 64 + j * 16 + (lane & 15);
        bfr[j] = *(const bf16v8*)&Bs[r * 64 + ((q ^ (r & 7)) * 8)];
      }
#pragma unroll
      for (int i = 0; i < 4; ++i)
#pragma unroll
        for (int j = 0; j < 4; ++j)
          acc[i][j] = __builtin_amdgcn_mfma_f32_16x16x32_bf16(af[i], bfr[j], acc[i][j], 0, 0, 0);
    }
    __syncthreads();
  }
#pragma unroll
  for (int i = 0; i < 4; ++i) {
    int row0 = tile_m + wm * 64 + i * 16 + (lane >> 4) * 4;
#pragma unroll
    for (int j = 0; j < 4; ++j) {
      int col = tile_n + wn * 64 + j * 16 + (lane & 15);
      float bv = bias ? bias[col] : 0.f;
#pragma unroll
      for (int p = 0; p < 4; ++p) {
        int row = row0 + p;
        if (row < M) Cb[(size_t)row * Nc + col] = f2bf(acc[i][j][p] + bv);
      }
    }
  }
}

// ---------------- fused edge softmax + aggregation (round-7 gather layout) ----------------
// lane owns cols lane*4..+3 (uint2) and 256+lane*2..+1 (dword).
template <int H>
static __device__ __forceinline__ void agg_body3(const float4 t,
                                                 const unsigned short* __restrict__ hfeat,
                                                 int lane, float acc[6]) {
  int s2 = __float_as_int(t.w);
  const unsigned short* hrow = hfeat + (size_t)s2 * HD;
  uint2 va = *(const uint2*)(hrow + lane * 4);
  unsigned vb = *(const unsigned*)(hrow + 256 + lane * 2);
  float wa = (H == 3) ? ((lane < 32) ? t.x : t.y) : t.x;
  float wc = (H == 3) ? t.z : t.x;
  acc[0] += wa * bf2f((unsigned short)(va.x & 0xffffu));
  acc[1] += wa * bf2f((unsigned short)(va.x >> 16));
  acc[2] += wa * bf2f((unsigned short)(va.y & 0xffffu));
  acc[3] += wa * bf2f((unsigned short)(va.y >> 16));
  acc[4] += wc * bf2f((unsigned short)(vb & 0xffffu));
  acc[5] += wc * bf2f((unsigned short)(vb >> 16));
}

template <int H>
static __device__ __forceinline__ void load_sc(const float* __restrict__ el,
                                               int s, const float erd[H], float sc[H]) {
  if constexpr (H == 3) {
    float4 e = ((const float4*)el)[s];
    sc[0] = lrelu(e.x + erd[0]);
    sc[1] = lrelu(e.y + erd[1]);
    sc[2] = lrelu(e.z + erd[2]);
  } else {
    sc[0] = lrelu(el[s] + erd[0]);
  }
}

template <int H>
__global__ __launch_bounds__(256) void agg_csr3(const int* __restrict__ offs,
                                                const int* __restrict__ deg,
                                                const int* __restrict__ srcs,
                                                const float* __restrict__ el,
                                                const float* __restrict__ er,
                                                const unsigned short* __restrict__ hfeat,
                                                const float* __restrict__ bias,
                                                unsigned short* __restrict__ outg) {
  __shared__ float wb[4][64][4];
  int wave = threadIdx.x >> 6, lane = threadIdx.x & 63;
  int d = blockIdx.x * 4 + wave;
  int o0 = offs[d], dg = deg[d];
  float erd[H];
  if constexpr (H == 3) {
    float4 e = ((const float4*)er)[d];
    erd[0] = e.x; erd[1] = e.y; erd[2] = e.z;
  } else {
    erd[0] = er[d];
  }
  float acc[6] = {0.f, 0.f, 0.f, 0.f, 0.f, 0.f};
  float wsum[H];
#pragma unroll
  for (int h = 0; h < H; ++h) wsum[h] = 0.f;

  if (dg <= 64) {
    bool has = lane < dg;
    int s = has ? srcs[o0 + lane] : 0;
    float sc[H], mh[H];
    load_sc<H>(el, s, erd, sc);
#pragma unroll
    for (int h = 0; h < H; ++h) {
      if (!has) sc[h] = -1e30f;
      mh[h] = sc[h];
#pragma unroll
      for (int off = 1; off < 64; off <<= 1) mh[h] = fmaxf(mh[h], __shfl_xor(mh[h], off));
    }
    float w0 = 0.f, w1 = 0.f, w2 = 0.f;
    if (has) {
      w0 = __expf(sc[0] - mh[0]);
      if constexpr (H == 3) {
        w1 = __expf(sc[1] - mh[1]);
        w2 = __expf(sc[2] - mh[2]);
      }
    }
    wsum[0] = w0;
    if constexpr (H == 3) { wsum[1] = w1; wsum[2] = w2; }
    *(float4*)&wb[wave][lane][0] = make_float4(w0, w1, w2, __int_as_float(s));
#pragma unroll 16
    for (int j = 0; j < dg; ++j) {
      float4 t = *(const float4*)&wb[wave][j][0];
      agg_body3<H>(t, hfeat, lane, acc);
    }
  } else {
    float mh[H];
#pragma unroll
    for (int h = 0; h < H; ++h) mh[h] = -1e30f;
    for (int e = lane; e < dg; e += 64) {
      int s = srcs[o0 + e];
      float sc[H];
      load_sc<H>(el, s, erd, sc);
#pragma unroll
      for (int h = 0; h < H; ++h) mh[h] = fmaxf(mh[h], sc[h]);
    }
#pragma unroll
    for (int h = 0; h < H; ++h) {
#pragma unroll
      for (int off = 1; off < 64; off <<= 1) mh[h] = fmaxf(mh[h], __shfl_xor(mh[h], off));
    }
    int nch = (dg + 63) >> 6;
    for (int ch = 0; ch < nch; ++ch) {
      int e = ch * 64 + lane;
      bool has = e < dg;
      int s = has ? srcs[o0 + e] : 0;
      float sc[H];
      load_sc<H>(el, s, erd, sc);
      float w0 = 0.f, w1 = 0.f, w2 = 0.f;
      if (has) {
        w0 = __expf(sc[0] - mh[0]);
        if constexpr (H == 3) {
          w1 = __expf(sc[1] - mh[1]);
          w2 = __expf(sc[2] - mh[2]);
        }
      }
      wsum[0] += w0;
      if constexpr (H == 3) { wsum[1] += w1; wsum[2] += w2; }
      *(float4*)&wb[wave][lane][0] = make_float4(w0, w1, w2, __int_as_float(s));
      int cnt = min(64, dg - ch * 64);
#pragma unroll 16
      for (int j = 0; j < cnt; ++j) {
        float4 t = *(const float4*)&wb[wave][j][0];
        agg_body3<H>(t, hfeat, lane, acc);
      }
    }
  }
#pragma unroll
  for (int h = 0; h < H; ++h) {
#pragma unroll
    for (int off = 1; off < 64; off <<= 1) wsum[h] += __shfl_xor(wsum[h], off);
  }
  float swA = (H == 3) ? ((lane < 32) ? wsum[0] : wsum[1]) : wsum[0];
  float swC = (H == 3) ? wsum[H - 1] : wsum[0];
  float invA = (dg > 0) ? 1.f / swA : 0.f;
  float invC = (dg > 0) ? 1.f / swC : 0.f;
  unsigned short* orow = outg + (size_t)d * HD;
  int cA = lane * 4, cB = 256 + lane * 2;
  float r0 = fmaxf(acc[0] * invA + bias[cA + 0], 0.f);
  float r1 = fmaxf(acc[1] * invA + bias[cA + 1], 0.f);
  float r2 = fmaxf(acc[2] * invA + bias[cA + 2], 0.f);
  float r3 = fmaxf(acc[3] * invA + bias[cA + 3], 0.f);
  float r4 = fmaxf(acc[4] * invC + bias[cB + 0], 0.f);
  float r5 = fmaxf(acc[5] * invC + bias[cB + 1], 0.f);
  uint2 pa;
  pa.x = (unsigned)f2bf(r0) | ((unsigned)f2bf(r1) << 16);
  pa.y = (unsigned)f2bf(r2) | ((unsigned)f2bf(r3) << 16);
  *(uint2*)(orow + cA) = pa;
  *(unsigned*)(orow + cB) = (unsigned)f2bf(r4) | ((unsigned)f2bf(r5) << 16);
}

// ---------------- graph max pool (graph_ids sorted; values >= 0) ----------------
__global__ void graph_pool(const unsigned short* __restrict__ g, const int* __restrict__ gid,
                           unsigned* __restrict__ gp) {
  int c = threadIdx.x;
  int n0 = blockIdx.x * 64;
  int nend = min(n0 + 64, NN);
  int cur = gid[n0];
  float mx = 0.f;
  for (int n = n0; n < nend; ++n) {
    int gg = gid[n];
    if (gg != cur) {
      atomicMax(&gp[cur * HD + c], __float_as_uint(mx));
      cur = gg; mx = 0.f;
    }
    mx = fmaxf(mx, bf2f(g[(size_t)n * HD + c]));
  }
  atomicMax(&gp[cur * HD + c], __float_as_uint(mx));
}

// ---------------- CNN branch: bf16 NHC pools ----------------
__global__ void maxpool_nhc(const unsigned short* __restrict__ in, unsigned short* __restrict__ out,
                            int Lin, int Lout, int total) {
  int idx = blockIdx.x * 256 + threadIdx.x;
  if (idx >= total) return;
  int c = idx & 127;
  int j = (idx >> 7) % Lout;
  int b = idx / (128 * Lout);
  const unsigned short* p = in + ((size_t)b * Lin + j * 3) * 128 + c;
  float m = bf2f(p[0]);
  m = fmaxf(m, bf2f(p[128]));
  m = fmaxf(m, bf2f(p[256]));
  out[idx] = f2bf(m);
}

// ---------------- fused head (includes c3 108-max pooling) ----------------
__global__ __launch_bounds__(256) void head_all(const unsigned* __restrict__ gpool,
                                                const unsigned short* __restrict__ c3bf,
                                                const float* __restrict__ fcgw,
                                                const float* __restrict__ fcgb,
                                                const float* __restrict__ tfw,
                                                const float* __restrict__ tfb,
                                                const float* __restrict__ w1s,
                                                const float* __restrict__ fc1w,
                                                const float* __restrict__ fc1b,
                                                const float* __restrict__ fc2w,
                                                const float* __restrict__ fc2b,
                                                const float* __restrict__ outw,
                                                const float* __restrict__ outb,
                                                float* __restrict__ out) {
  __shared__ float gl[HD];
  __shared__ float fvs[128];
  __shared__ float gcv[128];
  __shared__ float gc1[512];
  __shared__ float gc2[256];
  int b = blockIdx.x, tid = threadIdx.x;
  for (int c = tid; c < HD; c += 256) gl[c] = __uint_as_float(gpool[b * HD + c]);
  if (tid < 128) {
    const unsigned short* p = c3bf + (size_t)b * 108 * 128 + tid;
    float m = bf2f(p[0]);
    for (int t = 1; t < 108; ++t) m = fmaxf(m, bf2f(p[t * 128]));
    fvs[tid] = m;
  }
  __syncthreads();
  float wv = 1.f / (1.f + __expf(-w1s[0]));
  if (tid < 128) {
    float a = fcgb[tid];
    for (int k = 0; k < HD; ++k) a += gl[k] * fcgw[(size_t)k * 128 + tid];
    float g1 = fmaxf(a, 0.f);
    float s = tfb[tid];
    for (int k = 0; k < 128; ++k) s += fvs[k] * tfw[(size_t)k * 128 + tid];
    float s1 = fmaxf(s, 0.f);
    gcv[tid] = (1.f - wv) * g1 + wv * s1;
  }
  __syncthreads();
#pragma unroll
  for (int q = 0; q < 2; ++q) {
    int j = tid + q * 256;
    float a = fc1b[j];
    for (int k = 0; k < 128; ++k) a += gcv[k] * fc1w[(size_t)k * 512 + j];
    gc1[j] = fmaxf(a, 0.f);
  }
  __syncthreads();
  {
    float a = fc2b[tid];
    for (int k = 0; k < 512; ++k) a += gc1[k] * fc2w[(size_t)k * 256 + tid];
    gc2[tid] = fmaxf(a, 0.f);
  }
  __syncthreads();
  if (tid < 64) {
    float p0 = 0.f, p1 = 0.f;
#pragma unroll
    for (int q = 0; q < 4; ++q) {
      float v = gc2[tid + q * 64];
      p0 += v * outw[(tid + q * 64) * 2 + 0];
      p1 += v * outw[(tid + q * 64) * 2 + 1];
    }
#pragma unroll
    for (int off = 32; off; off >>= 1) {
      p0 += __shfl_down(p0, off);
      p1 += __shfl_down(p1, off);
    }
    if (tid == 0) {
      float o0 = fmaxf(p0 + outb[0], 0.f), o1 = fmaxf(p1 + outb[1], 0.f);
      float mm = fmaxf(o0, o1);
      float e0 = __expf(o0 - mm), e1 = __expf(o1 - mm);
      float inv = 1.f / (e0 + e1);
      out[b * 2 + 0] = e0 * inv;
      out[b * 2 + 1] = e1 * inv;
    }
  }
}

extern "C" void kernel_launch(void* const* d_in, const int* in_sizes, int n_in,
                              void* d_out, int out_size, void* d_ws, size_t ws_size,
                              hipStream_t stream) {
  const float* node_feat = (const float*)d_in[0];
  const int*   src  = (const int*)d_in[1];
  const int*   dst  = (const int*)d_in[2];
  const int*   gids = (const int*)d_in[3];
  const float* pad  = (const float*)d_in[4];
  const float* W1   = (const float*)d_in[5];
  const float* al1  = (const float*)d_in[6];
  const float* ar1  = (const float*)d_in[7];
  const float* b1   = (const float*)d_in[8];
  const float* W2   = (const float*)d_in[9];
  const float* al2  = (const float*)d_in[10];
  const float* ar2  = (const float*)d_in[11];
  const float* b2   = (const float*)d_in[12];
  const float* fcgw = (const float*)d_in[13];
  const float* fcgb = (const float*)d_in[14];
  const float* c1w  = (const float*)d_in[15];
  const float* c1b  = (const float*)d_in[16];
  const float* c2w  = (const float*)d_in[17];
  const float* c2b  = (const float*)d_in[18];
  const float* c3w  = (const float*)d_in[19];
  const float* c3b  = (const float*)d_in[20];
  const float* tfw  = (const float*)d_in[21];
  const float* tfb  = (const float*)d_in[22];
  const float* w1s  = (const float*)d_in[23];
  const float* fc1w = (const float*)d_in[24];
  const float* fc1b = (const float*)d_in[25];
  const float* fc2w = (const float*)d_in[26];
  const float* fc2b = (const float*)d_in[27];
  const float* outw = (const float*)d_in[28];
  const float* outb = (const float*)d_in[29];
  float* out = (float*)d_out;
  char* base = (char*)d_ws;

  // -------- workspace layout (bytes) --------
  constexpr size_t SZ_BIG = (size_t)NN * HD * 2;          // 76.8 MB
  unsigned short* hA   = (unsigned short*)(base + 0);     // region A: bf16 h table
  unsigned short* gB   = (unsigned short*)(base + SZ_BIG);// region B: bf16 g
  unsigned short* nfbf = gB;  // bf16 node_feat aliases region B (dead before agg1)
  size_t o = 2 * SZ_BIG;
  unsigned short* Wt1 = (unsigned short*)(base + o); o += 384 * 128 * 2;
  unsigned short* Wt2 = (unsigned short*)(base + o); o += 384 * 384 * 2;
  unsigned short* Wc1 = (unsigned short*)(base + o); o += 128 * 384 * 2;
  unsigned short* Wc2 = (unsigned short*)(base + o); o += 128 * 384 * 2;
  unsigned short* Wc3 = (unsigned short*)(base + o); o += 128 * 384 * 2;
  unsigned short* c3bf = (unsigned short*)(base + o); o += (size_t)BB * 108 * 128 * 2; // persists to head
  int* deg    = (int*)(base + o); o += (size_t)NN * 4;
  int* offs   = (int*)(base + o); o += (size_t)NN * 4;
  int* excl   = (int*)(base + o); o += (size_t)NN * 4;
  int* bsum   = (int*)(base + o); o += 2048;
  int* srcs   = (int*)(base + o); o += (size_t)EE * 4;
  int* rank   = (int*)(base + o); o += (size_t)EE * 4;
  float* el1  = (float*)(base + o); o += (size_t)NN * 4 * 4;   // padded stride 4
  float* er1  = (float*)(base + o); o += (size_t)NN * 4 * 4;
  float* el2  = (float*)(base + o); o += (size_t)NN * 4;       // contiguous with er2
  float* er2  = (float*)(base + o); o += (size_t)NN * 4;
  unsigned* gpool = (unsigned*)(base + o); o += (size_t)BB * HD * 4;

  // CNN scratch inside region A (dead before gemm1 writes hA), all bf16 NHC
  unsigned short* padbf = (unsigned short*)base;
  unsigned short* c1bf  = padbf + (size_t)BB * LSEQ * 128;
  unsigned short* p1bf  = c1bf + (size_t)BB * 998 * 128;
  unsigned short* c2bf  = p1bf + (size_t)BB * 332 * 128;
  unsigned short* p2bf  = c2bf + (size_t)BB * 330 * 128;

  // -------- fused prep --------
  prep_misc<<<PREP_BLOCKS, 256, 0, stream>>>(node_feat, nfbf, pad, padbf, deg, el2, gpool,
                                             W1, Wt1, W2, Wt2, c1w, Wc1, c2w, Wc2, c3w, Wc3);

  // -------- CNN branch --------
  gemm_mfma<<<dim3(1, 8, BB), 256, 0, stream>>>(padbf, 128, Wc1, c1bf, 998, 384, 128, c1b,
                                                (long)LSEQ * 128, (long)998 * 128);
  maxpool_nhc<<<(BB * 332 * 128 + 255) / 256, 256, 0, stream>>>(c1bf, p1bf, 998, 332, BB * 332 * 128);
  gemm_mfma<<<dim3(1, 3, BB), 256, 0, stream>>>(p1bf, 128, Wc2, c2bf, 330, 384, 128, c2b,
                                                (long)332 * 128, (long)330 * 128);
  maxpool_nhc<<<(BB * 110 * 128 + 255) / 256, 256, 0, stream>>>(c2bf, p2bf, 330, 110, BB * 110 * 128);
  gemm_mfma<<<dim3(1, 1, BB), 256, 0, stream>>>(p2bf, 128, Wc3, c3bf, 108, 384, 128, c3b,
                                                (long)110 * 128, (long)108 * 128);

  // -------- CSR build --------
  hist_k<<<EE / 1024, 256, 0, stream>>>(dst, deg, rank);
  scan1_k<<<NB1, 256, 0, stream>>>(deg, excl, bsum);
  scan2p<<<1, 512, 0, stream>>>(bsum);
  scan3_k<<<NB1, 256, 0, stream>>>(excl, bsum, offs);
  scatter_k<<<EE / 1024, 256, 0, stream>>>(src, dst, rank, offs, srcs);

  // -------- GAT layer 1 (GEMM + fused el/er) --------
  gemm_nres<2, true><<<dim3(3, (NMT + 9) / 10), 512, 0, stream>>>(
      nfbf, Wt1, hA, al1, ar1, el1, er1, NN, HD, NMT, 10);
  agg_csr3<3><<<NN / 4, 256, 0, stream>>>(offs, deg, srcs, el1, er1, hA, b1, gB);

  // -------- GAT layer 2 (GEMM + fused el/er) --------
  gemm_nres<6, false><<<dim3(3, (NMT + 9) / 10), 512, 0, stream>>>(
      gB, Wt2, hA, al2, ar2, el2, er2, NN, HD, NMT, 10);
  agg_csr3<1><<<NN / 4, 256, 0, stream>>>(offs, deg, srcs, el2, er2, hA, b2, gB);

  // -------- graph pooling + fused head --------
  graph_pool<<<(NN + 63) / 64, 384, 0, stream>>>(gB, gids, gpool);
  head_all<<<BB, 256, 0, stream>>>(gpool, c3bf, fcgw, fcgb, tfw, tfb, w1s,
                                   fc1w, fc1b, fc2w, fc2b, outw, outb, out);
}